// Round 4
// baseline (2369.629 us; speedup 1.0000x reference)
//
#include <hip/hip_runtime.h>
#include <hip/hip_bf16.h>
#include <stdint.h>

#define N_NODES 524288
#define N_EDGES 4194304
#define N_GRAPHS 4096
#define HDIM 32
#define NLAYERS 3
#define KPOOL 30

// ---------- degree (int counts) ----------
__global__ void k_deg(const int* __restrict__ dst, int* __restrict__ deg) {
    int e = blockIdx.x * 256 + threadIdx.x;
    if (e < N_EDGES) atomicAdd(&deg[dst[e]], 1);
}

// dinv = f32(1 / f32(sqrt(deg+1)))  -- two correctly-rounded f32 ops, like 1/np.sqrt
__global__ void k_dinv(const int* __restrict__ deg, float* __restrict__ dinv) {
    int n = blockIdx.x * 256 + threadIdx.x;
    if (n < N_NODES) {
        float d = (float)(deg[n] + 1);              // exact
        float sq = (float)sqrt((double)d);          // correctly-rounded f32 sqrt
        dinv[n] = (float)(1.0 / (double)sq);        // correctly-rounded f32 div
    }
}

// ---------- exclusive scan of deg -> offs ----------
__global__ void k_scan_block(const int* __restrict__ deg, int* __restrict__ offs,
                             int* __restrict__ bsum) {
    __shared__ int tmp[256];
    int t = threadIdx.x;
    int idx = blockIdx.x * 256 + t;
    int v = deg[idx];
    tmp[t] = v;
    __syncthreads();
    for (int d = 1; d < 256; d <<= 1) {
        int add = (t >= d) ? tmp[t - d] : 0;
        __syncthreads();
        tmp[t] += add;
        __syncthreads();
    }
    offs[idx] = tmp[t] - v;
    if (t == 255) bsum[blockIdx.x] = tmp[t];
}

__global__ void k_scan_bsums(const int* __restrict__ bsum, int* __restrict__ boff) {
    __shared__ int tmp[256];
    int t = threadIdx.x;
    int loc[8];
    int s = 0;
    for (int i = 0; i < 8; ++i) { loc[i] = bsum[t * 8 + i]; s += loc[i]; }
    tmp[t] = s;
    __syncthreads();
    for (int d = 1; d < 256; d <<= 1) {
        int add = (t >= d) ? tmp[t - d] : 0;
        __syncthreads();
        tmp[t] += add;
        __syncthreads();
    }
    int run = tmp[t] - s;
    for (int i = 0; i < 8; ++i) { boff[t * 8 + i] = run; run += loc[i]; }
}

__global__ void k_scan_add(int* __restrict__ offs, const int* __restrict__ boff,
                           int* __restrict__ cursor) {
    int idx = blockIdx.x * 256 + threadIdx.x;
    int v = offs[idx] + boff[blockIdx.x];
    offs[idx] = v;
    cursor[idx] = v;
    if (idx == 0) offs[N_NODES] = N_EDGES;
}

// ---------- CSR scatter of EDGE IDS (order fixed by per-node sort below) ----------
__global__ void k_scatter(const int* __restrict__ dst, int* __restrict__ cursor,
                          int* __restrict__ csr_eid) {
    int e = blockIdx.x * 256 + threadIdx.x;
    if (e < N_EDGES) {
        int d = dst[e];
        int pos = atomicAdd(&cursor[d], 1);
        csr_eid[pos] = e;
    }
}

// ---------- per-node insertion sort of edge ids (edge-order-stable CSR) ----------
__global__ void k_sortseg(const int* __restrict__ offs, int* __restrict__ eid) {
    int n = blockIdx.x * 256 + threadIdx.x;
    if (n >= N_NODES) return;
    int b = offs[n], e2 = offs[n + 1];
    for (int i = b + 1; i < e2; ++i) {
        int v = eid[i];
        int j = i - 1;
        while (j >= b && eid[j] > v) { eid[j + 1] = eid[j]; --j; }
        eid[j + 1] = v;
    }
}

// ---------- embedding gather (exact) ----------
__global__ void k_embed(const int* __restrict__ xz, const float* __restrict__ emb,
                        float* __restrict__ x) {
    int gid = blockIdx.x * 256 + threadIdx.x;
    int n = gid >> 5, c = gid & 31;
    x[gid] = emb[xz[n] * HDIM + c];
}

// ---------- rs = f32(1 / f32(sqrt(f32(rvar + 1e-5)))) ----------
__global__ void k_bnprep(const float* __restrict__ rvar, float* __restrict__ rs) {
    int i = threadIdx.x;
    if (i < NLAYERS * HDIM) {
        float rv = __fadd_rn(rvar[i], 1e-5f);
        float sq = (float)sqrt((double)rv);
        rs[i] = (float)(1.0 / (double)sq);
    }
}

// ---------- dense h = x @ Wc : sequential-k f32 FMA per output element ----------
__global__ void k_matmul(const float* __restrict__ x, const float* __restrict__ Wc,
                         float* __restrict__ h) {
    __shared__ float Wl[HDIM * HDIM];
    __shared__ float xt[256];
    int t = threadIdx.x;
    int base = blockIdx.x * 256;
    for (int i = t; i < HDIM * HDIM; i += 256) Wl[i] = Wc[i];
    xt[t] = x[base + t];
    __syncthreads();
    int nl = t >> 5, c = t & 31;
    float acc = 0.0f;
#pragma unroll
    for (int k = 0; k < HDIM; ++k) acc = __fmaf_rn(xt[nl * HDIM + k], Wl[k * HDIM + c], acc);
    h[base + t] = acc;
}

// ---------- aggregation, strict f32 op-order replication of the reference ----------
__global__ void k_agg(const float* __restrict__ h, const float* __restrict__ dinv,
                      const int* __restrict__ offs, const int* __restrict__ csr_eid,
                      const int* __restrict__ src,
                      const float* __restrict__ bc, const float* __restrict__ rmean,
                      const float* __restrict__ rs, const float* __restrict__ gamma,
                      const float* __restrict__ beta, float* __restrict__ xout) {
    int gid = blockIdx.x * 256 + threadIdx.x;
    int n = gid >> 5, c = gid & 31;
    float di = dinv[n];
    float accE = 0.0f;  // np.add.at: sequential in edge-id order
    int beg = offs[n], end = offs[n + 1];
    for (int i = beg; i < end; ++i) {
        int e = csr_eid[i];
        int s = src[e];
        float en = __fmul_rn(dinv[s], di);                 // enorm[e]
        float m  = __fmul_rn(h[s * HDIM + c], en);         // h[src]*enorm
        accE = __fadd_rn(accE, m);
    }
    float sn = __fmul_rn(di, di);                          // self_norm
    float t1 = __fmul_rn(h[gid], sn);
    float a2 = __fadd_rn(accE, t1);                        // scatter + self
    float a3 = __fadd_rn(a2, bc[c]);                       // + bc
    float tt = __fsub_rn(a3, rmean[c]);
    float u  = __fmul_rn(tt, rs[c]);
    float v  = __fmul_rn(u, gamma[c]);
    float xn = __fadd_rn(v, beta[c]);
    xout[gid] = (xn > 0.0f) ? xn : 0.0f;                   // relu, forces +0.0
}

// ---------- per-graph starts ----------
__global__ void k_starts(const int* __restrict__ batch, int* __restrict__ start) {
    int n = blockIdx.x * 256 + threadIdx.x;
    if (n >= N_NODES) return;
    int bn = batch[n];
    int bp = (n == 0) ? -1 : batch[n - 1];
    for (int g = bp + 1; g <= bn; ++g) start[g] = n;
    if (n == N_NODES - 1) {
        for (int g = bn + 1; g <= N_GRAPHS; ++g) start[g] = N_NODES;
    }
}

// ---------- sort-pool (f32 keys, stable) + MLP (f64 accumulate) ----------
__global__ void k_pool_mlp(const float* __restrict__ x, const int* __restrict__ start,
                           const float* __restrict__ W1, const float* __restrict__ b1,
                           const float* __restrict__ W2, const float* __restrict__ b2,
                           const float* __restrict__ W3, const float* __restrict__ b3,
                           float* __restrict__ out) {
    int g = blockIdx.x;
    int t = threadIdx.x;  // 64 threads = 1 wave
    int s = start[g], e = start[g + 1];
    int cnt = e - s;

    __shared__ int sel[KPOOL];
    __shared__ float pl[KPOOL * HDIM];
    __shared__ double part[64];
    __shared__ double h1[HDIM];
    __shared__ double h2[HDIM / 2];

    // iterative top-K: key = (f32 bits << 32) | ~index; values >= 0 so bits monotone
    unsigned long long prev = ~0ull;
    for (int k = 0; k < KPOOL; ++k) {
        if (k < cnt) {
            unsigned long long best = 0ull;
            for (int n = s + t; n < e; n += 64) {
                float v = x[n * HDIM + (HDIM - 1)];
                unsigned long long key =
                    ((unsigned long long)__float_as_uint(v) << 32) | (unsigned int)(~n);
                if (key < prev && key > best) best = key;
            }
            for (int off = 32; off; off >>= 1) {
                unsigned long long o = __shfl_down(best, off);
                if (o > best) best = o;
            }
            best = __shfl(best, 0);
            prev = best;
            if (t == 0) sel[k] = (int)(~((unsigned int)(best & 0xffffffffull)));
        } else {
            if (t == 0) sel[k] = -1;
        }
    }
    __syncthreads();

    for (int idx = t; idx < KPOOL * HDIM; idx += 64) {
        int k = idx >> 5, c = idx & 31;
        int n = sel[k];
        pl[idx] = (n >= 0) ? x[n * HDIM + c] : 0.0f;
    }
    __syncthreads();

    {
        int j = t & 31;
        int half = t >> 5;
        double acc = 0.0;
        int r0 = half * (KPOOL * HDIM / 2);
        for (int r = r0; r < r0 + KPOOL * HDIM / 2; ++r)
            acc += (double)pl[r] * (double)W1[r * HDIM + j];
        part[t] = acc;
    }
    __syncthreads();
    if (t < HDIM) {
        double v = part[t] + part[t + 32] + (double)b1[t];
        h1[t] = (v > 0.0) ? v : 0.0;
    }
    __syncthreads();

    if (t < HDIM / 2) {
        double a2 = (double)b2[t];
        for (int i = 0; i < HDIM; ++i) a2 += h1[i] * (double)W2[i * (HDIM / 2) + t];
        h2[t] = (a2 > 0.0) ? a2 : 0.0;
    }
    __syncthreads();

    if (t == 0) {
        double o = (double)b3[0];
        for (int i = 0; i < HDIM / 2; ++i) o += h2[i] * (double)W3[i];
        out[g] = (float)o;
    }
}

extern "C" void kernel_launch(void* const* d_in, const int* in_sizes, int n_in,
                              void* d_out, int out_size, void* d_ws, size_t ws_size,
                              hipStream_t stream) {
    const int*   xz    = (const int*)d_in[0];
    const int*   src   = (const int*)d_in[1];            // edge_index[0]
    const int*   dst   = (const int*)d_in[1] + N_EDGES;  // edge_index[1]
    const int*   batch = (const int*)d_in[2];
    const float* emb   = (const float*)d_in[3];
    const float* Wc    = (const float*)d_in[4];
    const float* bc    = (const float*)d_in[5];
    const float* gamma = (const float*)d_in[6];
    const float* beta  = (const float*)d_in[7];
    const float* rmean = (const float*)d_in[8];
    const float* rvar  = (const float*)d_in[9];
    const float* W1    = (const float*)d_in[10];
    const float* b1    = (const float*)d_in[11];
    const float* W2    = (const float*)d_in[12];
    const float* b2    = (const float*)d_in[13];
    const float* W3    = (const float*)d_in[14];
    const float* b3    = (const float*)d_in[15];
    float* out = (float*)d_out;

    // workspace carve-up (256B aligned). Total ~159 MB (same as proven-to-run R1).
    char* p = (char*)d_ws;
    auto carve = [&](size_t bytes) {
        void* q = (void*)p;
        p += (bytes + 255) & ~size_t(255);
        return q;
    };
    int*   deg     = (int*)carve(N_NODES * 4);
    int*   offs    = (int*)carve((N_NODES + 1) * 4);
    int*   bsum    = (int*)carve(2048 * 4);
    int*   boff    = (int*)carve(2048 * 4);
    int*   cursor  = (int*)carve(N_NODES * 4);
    int*   csr_eid = (int*)carve((size_t)N_EDGES * 4);
    float* dinv    = (float*)carve(N_NODES * 4);
    int*   start   = (int*)carve((N_GRAPHS + 1) * 4);
    float* rs      = (float*)carve(NLAYERS * HDIM * 4);
    float* xb      = (float*)carve((size_t)N_NODES * HDIM * 4);
    float* hb      = (float*)carve((size_t)N_NODES * HDIM * 4);

    hipMemsetAsync(deg, 0, N_NODES * 4, stream);

    k_deg<<<N_EDGES / 256, 256, 0, stream>>>(dst, deg);
    k_dinv<<<N_NODES / 256, 256, 0, stream>>>(deg, dinv);
    k_scan_block<<<N_NODES / 256, 256, 0, stream>>>(deg, offs, bsum);
    k_scan_bsums<<<1, 256, 0, stream>>>(bsum, boff);
    k_scan_add<<<N_NODES / 256, 256, 0, stream>>>(offs, boff, cursor);
    k_scatter<<<N_EDGES / 256, 256, 0, stream>>>(dst, cursor, csr_eid);
    k_sortseg<<<N_NODES / 256, 256, 0, stream>>>(offs, csr_eid);
    k_embed<<<(N_NODES * HDIM) / 256, 256, 0, stream>>>(xz, emb, xb);
    k_bnprep<<<1, 128, 0, stream>>>(rvar, rs);
    k_starts<<<N_NODES / 256, 256, 0, stream>>>(batch, start);

    for (int l = 0; l < NLAYERS; ++l) {
        k_matmul<<<(N_NODES * HDIM) / 256, 256, 0, stream>>>(xb, Wc + l * HDIM * HDIM, hb);
        k_agg<<<(N_NODES * HDIM) / 256, 256, 0, stream>>>(
            hb, dinv, offs, csr_eid, src,
            bc + l * HDIM, rmean + l * HDIM, rs + l * HDIM,
            gamma + l * HDIM, beta + l * HDIM, xb);
    }

    k_pool_mlp<<<N_GRAPHS, 64, 0, stream>>>(xb, start, W1, b1, W2, b2, W3, b3, out);
}

// Round 5
// 2039.060 us; speedup vs baseline: 1.1621x; 1.1621x over previous
//
#include <hip/hip_runtime.h>
#include <hip/hip_bf16.h>
#include <stdint.h>

#define N_NODES 524288
#define N_EDGES 4194304
#define N_GRAPHS 4096
#define HDIM 32
#define NLAYERS 3
#define KPOOL 30

// ---------- degree (int counts) ----------
__global__ void k_deg(const int* __restrict__ dst, int* __restrict__ deg) {
    int e = blockIdx.x * 256 + threadIdx.x;
    if (e < N_EDGES) atomicAdd(&deg[dst[e]], 1);
}

// dinv = f32(1 / f32(sqrt(deg+1)))
__global__ void k_dinv(const int* __restrict__ deg, float* __restrict__ dinv) {
    int n = blockIdx.x * 256 + threadIdx.x;
    if (n < N_NODES) {
        float d = (float)(deg[n] + 1);
        float sq = (float)sqrt((double)d);
        dinv[n] = (float)(1.0 / (double)sq);
    }
}

// ---------- exclusive scan of deg -> offs ----------
__global__ void k_scan_block(const int* __restrict__ deg, int* __restrict__ offs,
                             int* __restrict__ bsum) {
    __shared__ int tmp[256];
    int t = threadIdx.x;
    int idx = blockIdx.x * 256 + t;
    int v = deg[idx];
    tmp[t] = v;
    __syncthreads();
    for (int d = 1; d < 256; d <<= 1) {
        int add = (t >= d) ? tmp[t - d] : 0;
        __syncthreads();
        tmp[t] += add;
        __syncthreads();
    }
    offs[idx] = tmp[t] - v;
    if (t == 255) bsum[blockIdx.x] = tmp[t];
}

__global__ void k_scan_bsums(const int* __restrict__ bsum, int* __restrict__ boff) {
    __shared__ int tmp[256];
    int t = threadIdx.x;
    int loc[8];
    int s = 0;
    for (int i = 0; i < 8; ++i) { loc[i] = bsum[t * 8 + i]; s += loc[i]; }
    tmp[t] = s;
    __syncthreads();
    for (int d = 1; d < 256; d <<= 1) {
        int add = (t >= d) ? tmp[t - d] : 0;
        __syncthreads();
        tmp[t] += add;
        __syncthreads();
    }
    int run = tmp[t] - s;
    for (int i = 0; i < 8; ++i) { boff[t * 8 + i] = run; run += loc[i]; }
}

__global__ void k_scan_add(int* __restrict__ offs, const int* __restrict__ boff,
                           int* __restrict__ cursor) {
    int idx = blockIdx.x * 256 + threadIdx.x;
    int v = offs[idx] + boff[blockIdx.x];
    offs[idx] = v;
    cursor[idx] = v;
    if (idx == 0) offs[N_NODES] = N_EDGES;
}

// ---------- CSR scatter of EDGE IDS ----------
__global__ void k_scatter(const int* __restrict__ dst, int* __restrict__ cursor,
                          int* __restrict__ csr) {
    int e = blockIdx.x * 256 + threadIdx.x;
    if (e < N_EDGES) {
        int d = dst[e];
        int pos = atomicAdd(&cursor[d], 1);
        csr[pos] = e;
    }
}

// ---------- fused: per-node insertion sort of eids, then eid -> src in place ----------
__global__ void k_sortconv(const int* __restrict__ offs, const int* __restrict__ src,
                           int* __restrict__ csr) {
    int n = blockIdx.x * 256 + threadIdx.x;
    if (n >= N_NODES) return;
    int b = offs[n], e2 = offs[n + 1];
    for (int i = b + 1; i < e2; ++i) {
        int v = csr[i];
        int j = i - 1;
        while (j >= b && csr[j] > v) { csr[j + 1] = csr[j]; --j; }
        csr[j + 1] = v;
    }
    // convert: eid -> src (order now fixed; values become source node ids)
    for (int i = b; i < e2; ++i) csr[i] = src[csr[i]];
}

// ---------- rs = f32(1 / f32(sqrt(f32(rvar + 1e-5)))) ----------
__global__ void k_bnprep(const float* __restrict__ rvar, float* __restrict__ rs) {
    int i = threadIdx.x;
    if (i < NLAYERS * HDIM) {
        float rv = __fadd_rn(rvar[i], 1e-5f);
        float sq = (float)sqrt((double)rv);
        rs[i] = (float)(1.0 / (double)sq);
    }
}

// ---------- fused embed + matmul layer0: h0 = emb[xz] @ Wc0 ----------
__global__ void k_embed_mm(const int* __restrict__ xz, const float* __restrict__ emb,
                           const float* __restrict__ Wc, float* __restrict__ h) {
    __shared__ float Wl[HDIM * HDIM];
    __shared__ float xt[256];
    int t = threadIdx.x;
    int base = blockIdx.x * 256;
    for (int i = t; i < HDIM * HDIM; i += 256) Wl[i] = Wc[i];
    {
        int gid = base + t;
        int n = gid >> 5, c = gid & 31;
        xt[t] = emb[xz[n] * HDIM + c];
    }
    __syncthreads();
    int nl = t >> 5, c = t & 31;
    float acc = 0.0f;
#pragma unroll
    for (int k = 0; k < HDIM; ++k) acc = __fmaf_rn(xt[nl * HDIM + k], Wl[k * HDIM + c], acc);
    h[base + t] = acc;
}

// ---------- agg phase (strict f32 op order), shared by fused kernels ----------
__device__ __forceinline__ float agg_phase(const float* __restrict__ h,
                                           const float* __restrict__ dinv,
                                           const int* __restrict__ offs,
                                           const int* __restrict__ csr_src,
                                           const float* __restrict__ bc,
                                           const float* __restrict__ rmean,
                                           const float* __restrict__ rs,
                                           const float* __restrict__ gamma,
                                           const float* __restrict__ beta,
                                           int gid) {
    int n = gid >> 5, c = gid & 31;
    float di = dinv[n];
    float accE = 0.0f;  // np.add.at: sequential in edge-id order
    int beg = offs[n], end = offs[n + 1];
    if (beg < end) {
        int s = csr_src[beg];
        float hv = h[s * HDIM + c];
        float dv = dinv[s];
        for (int i = beg + 1; i < end; ++i) {
            int s1 = csr_src[i];          // prefetch next edge
            float hv1 = h[s1 * HDIM + c];
            float dv1 = dinv[s1];
            accE = __fadd_rn(accE, __fmul_rn(hv, __fmul_rn(dv, di)));
            hv = hv1; dv = dv1;
        }
        accE = __fadd_rn(accE, __fmul_rn(hv, __fmul_rn(dv, di)));
    }
    float sn = __fmul_rn(di, di);
    float t1 = __fmul_rn(h[gid], sn);
    float a2 = __fadd_rn(accE, t1);
    float a3 = __fadd_rn(a2, bc[c]);
    float tt = __fsub_rn(a3, rmean[c]);
    float u  = __fmul_rn(tt, rs[c]);
    float v  = __fmul_rn(u, gamma[c]);
    float xn = __fadd_rn(v, beta[c]);
    return (xn > 0.0f) ? xn : 0.0f;
}

// ---------- fused agg(BN,ReLU) + next-layer matmul ----------
__global__ void k_agg_mm(const float* __restrict__ h, const float* __restrict__ dinv,
                         const int* __restrict__ offs, const int* __restrict__ csr_src,
                         const float* __restrict__ bc, const float* __restrict__ rmean,
                         const float* __restrict__ rs, const float* __restrict__ gamma,
                         const float* __restrict__ beta,
                         const float* __restrict__ Wnext, float* __restrict__ hout) {
    __shared__ float Wl[HDIM * HDIM];
    __shared__ float xt[256];
    int t = threadIdx.x;
    int base = blockIdx.x * 256;
    for (int i = t; i < HDIM * HDIM; i += 256) Wl[i] = Wnext[i];
    xt[t] = agg_phase(h, dinv, offs, csr_src, bc, rmean, rs, gamma, beta, base + t);
    __syncthreads();
    int nl = t >> 5, c = t & 31;
    float acc = 0.0f;
#pragma unroll
    for (int k = 0; k < HDIM; ++k) acc = __fmaf_rn(xt[nl * HDIM + k], Wl[k * HDIM + c], acc);
    hout[base + t] = acc;
}

// ---------- last agg (no matmul after) ----------
__global__ void k_agg_last(const float* __restrict__ h, const float* __restrict__ dinv,
                           const int* __restrict__ offs, const int* __restrict__ csr_src,
                           const float* __restrict__ bc, const float* __restrict__ rmean,
                           const float* __restrict__ rs, const float* __restrict__ gamma,
                           const float* __restrict__ beta, float* __restrict__ xout) {
    int gid = blockIdx.x * 256 + threadIdx.x;
    xout[gid] = agg_phase(h, dinv, offs, csr_src, bc, rmean, rs, gamma, beta, gid);
}

// ---------- per-graph starts ----------
__global__ void k_starts(const int* __restrict__ batch, int* __restrict__ start) {
    int n = blockIdx.x * 256 + threadIdx.x;
    if (n >= N_NODES) return;
    int bn = batch[n];
    int bp = (n == 0) ? -1 : batch[n - 1];
    for (int g = bp + 1; g <= bn; ++g) start[g] = n;
    if (n == N_NODES - 1) {
        for (int g = bn + 1; g <= N_GRAPHS; ++g) start[g] = N_NODES;
    }
}

// ---------- sort-pool (f32 keys, stable) + MLP (f64 accumulate) ----------
__global__ void k_pool_mlp(const float* __restrict__ x, const int* __restrict__ start,
                           const float* __restrict__ W1, const float* __restrict__ b1,
                           const float* __restrict__ W2, const float* __restrict__ b2,
                           const float* __restrict__ W3, const float* __restrict__ b3,
                           float* __restrict__ out) {
    int g = blockIdx.x;
    int t = threadIdx.x;  // 64 threads = 1 wave
    int s = start[g], e = start[g + 1];
    int cnt = e - s;

    __shared__ int sel[KPOOL];
    __shared__ float pl[KPOOL * HDIM];
    __shared__ double part[64];
    __shared__ double h1[HDIM];
    __shared__ double h2[HDIM / 2];

    unsigned long long prev = ~0ull;
    for (int k = 0; k < KPOOL; ++k) {
        if (k < cnt) {
            unsigned long long best = 0ull;
            for (int n = s + t; n < e; n += 64) {
                float v = x[n * HDIM + (HDIM - 1)];
                unsigned long long key =
                    ((unsigned long long)__float_as_uint(v) << 32) | (unsigned int)(~n);
                if (key < prev && key > best) best = key;
            }
            for (int off = 32; off; off >>= 1) {
                unsigned long long o = __shfl_down(best, off);
                if (o > best) best = o;
            }
            best = __shfl(best, 0);
            prev = best;
            if (t == 0) sel[k] = (int)(~((unsigned int)(best & 0xffffffffull)));
        } else {
            if (t == 0) sel[k] = -1;
        }
    }
    __syncthreads();

    for (int idx = t; idx < KPOOL * HDIM; idx += 64) {
        int k = idx >> 5, c = idx & 31;
        int n = sel[k];
        pl[idx] = (n >= 0) ? x[n * HDIM + c] : 0.0f;
    }
    __syncthreads();

    {
        int j = t & 31;
        int half = t >> 5;
        double acc = 0.0;
        int r0 = half * (KPOOL * HDIM / 2);
        for (int r = r0; r < r0 + KPOOL * HDIM / 2; ++r)
            acc += (double)pl[r] * (double)W1[r * HDIM + j];
        part[t] = acc;
    }
    __syncthreads();
    if (t < HDIM) {
        double v = part[t] + part[t + 32] + (double)b1[t];
        h1[t] = (v > 0.0) ? v : 0.0;
    }
    __syncthreads();

    if (t < HDIM / 2) {
        double a2 = (double)b2[t];
        for (int i = 0; i < HDIM; ++i) a2 += h1[i] * (double)W2[i * (HDIM / 2) + t];
        h2[t] = (a2 > 0.0) ? a2 : 0.0;
    }
    __syncthreads();

    if (t == 0) {
        double o = (double)b3[0];
        for (int i = 0; i < HDIM / 2; ++i) o += h2[i] * (double)W3[i];
        out[g] = (float)o;
    }
}

extern "C" void kernel_launch(void* const* d_in, const int* in_sizes, int n_in,
                              void* d_out, int out_size, void* d_ws, size_t ws_size,
                              hipStream_t stream) {
    const int*   xz    = (const int*)d_in[0];
    const int*   src   = (const int*)d_in[1];            // edge_index[0]
    const int*   dst   = (const int*)d_in[1] + N_EDGES;  // edge_index[1]
    const int*   batch = (const int*)d_in[2];
    const float* emb   = (const float*)d_in[3];
    const float* Wc    = (const float*)d_in[4];
    const float* bc    = (const float*)d_in[5];
    const float* gamma = (const float*)d_in[6];
    const float* beta  = (const float*)d_in[7];
    const float* rmean = (const float*)d_in[8];
    const float* rvar  = (const float*)d_in[9];
    const float* W1    = (const float*)d_in[10];
    const float* b1    = (const float*)d_in[11];
    const float* W2    = (const float*)d_in[12];
    const float* b2    = (const float*)d_in[13];
    const float* W3    = (const float*)d_in[14];
    const float* b3    = (const float*)d_in[15];
    float* out = (float*)d_out;

    // workspace carve-up (256B aligned). Total ~159 MB (proven-safe R4 footprint).
    char* p = (char*)d_ws;
    auto carve = [&](size_t bytes) {
        void* q = (void*)p;
        p += (bytes + 255) & ~size_t(255);
        return q;
    };
    int*   deg    = (int*)carve(N_NODES * 4);
    int*   offs   = (int*)carve((N_NODES + 1) * 4);
    int*   bsum   = (int*)carve(2048 * 4);
    int*   boff   = (int*)carve(2048 * 4);
    int*   cursor = (int*)carve(N_NODES * 4);
    int*   csr    = (int*)carve((size_t)N_EDGES * 4);   // eids, then src after sortconv
    float* dinv   = (float*)carve(N_NODES * 4);
    int*   start  = (int*)carve((N_GRAPHS + 1) * 4);
    float* rs     = (float*)carve(NLAYERS * HDIM * 4);
    float* bufA   = (float*)carve((size_t)N_NODES * HDIM * 4);
    float* bufB   = (float*)carve((size_t)N_NODES * HDIM * 4);

    hipMemsetAsync(deg, 0, N_NODES * 4, stream);

    k_deg<<<N_EDGES / 256, 256, 0, stream>>>(dst, deg);
    k_dinv<<<N_NODES / 256, 256, 0, stream>>>(deg, dinv);
    k_scan_block<<<N_NODES / 256, 256, 0, stream>>>(deg, offs, bsum);
    k_scan_bsums<<<1, 256, 0, stream>>>(bsum, boff);
    k_scan_add<<<N_NODES / 256, 256, 0, stream>>>(offs, boff, cursor);
    k_scatter<<<N_EDGES / 256, 256, 0, stream>>>(dst, cursor, csr);
    k_sortconv<<<N_NODES / 256, 256, 0, stream>>>(offs, src, csr);
    k_bnprep<<<1, 128, 0, stream>>>(rvar, rs);
    k_starts<<<N_NODES / 256, 256, 0, stream>>>(batch, start);

    const int NG = (N_NODES * HDIM) / 256;
    // h0 = emb[xz] @ Wc0  -> A
    k_embed_mm<<<NG, 256, 0, stream>>>(xz, emb, Wc + 0 * HDIM * HDIM, bufA);
    // x1 = aggBN(h0); h1 = x1 @ Wc1 -> B
    k_agg_mm<<<NG, 256, 0, stream>>>(bufA, dinv, offs, csr,
        bc + 0 * HDIM, rmean + 0 * HDIM, rs + 0 * HDIM, gamma + 0 * HDIM, beta + 0 * HDIM,
        Wc + 1 * HDIM * HDIM, bufB);
    // x2 = aggBN(h1); h2 = x2 @ Wc2 -> A
    k_agg_mm<<<NG, 256, 0, stream>>>(bufB, dinv, offs, csr,
        bc + 1 * HDIM, rmean + 1 * HDIM, rs + 1 * HDIM, gamma + 1 * HDIM, beta + 1 * HDIM,
        Wc + 2 * HDIM * HDIM, bufA);
    // x3 = aggBN(h2) -> B
    k_agg_last<<<NG, 256, 0, stream>>>(bufA, dinv, offs, csr,
        bc + 2 * HDIM, rmean + 2 * HDIM, rs + 2 * HDIM, gamma + 2 * HDIM, beta + 2 * HDIM,
        bufB);

    k_pool_mlp<<<N_GRAPHS, 64, 0, stream>>>(bufB, start, W1, b1, W2, b2, W3, b3, out);
}

// Round 6
// 1774.413 us; speedup vs baseline: 1.3354x; 1.1491x over previous
//
#include <hip/hip_runtime.h>
#include <hip/hip_bf16.h>
#include <stdint.h>

#define N_NODES 524288
#define N_EDGES 4194304
#define N_GRAPHS 4096
#define HDIM 32
#define NLAYERS 3
#define KPOOL 30

#define NBUCKET 1024
#define BSHIFT 9             // bucket = dst >> 9
#define NPB 512              // nodes per bucket
#define NCOPY 8              // per-XCD slice copies
#define HIST_SZ (NBUCKET * NCOPY)

// ---------- histogram of edges per (bucket, xcd-slice) ----------
__global__ void k_hist(const int* __restrict__ dst, int* __restrict__ ghist) {
    __shared__ int lh[NBUCKET];
    int t = threadIdx.x;
    for (int i = t; i < NBUCKET; i += 256) lh[i] = 0;
    __syncthreads();
    int base = blockIdx.x * 2048;
    for (int i = t; i < 2048; i += 256) {
        int d = dst[base + i];
        atomicAdd(&lh[d >> BSHIFT], 1);
    }
    __syncthreads();
    int c = blockIdx.x & 7;
    for (int i = t; i < NBUCKET; i += 256) {
        int v = lh[i];
        if (v) atomicAdd(&ghist[i * NCOPY + c], v);
    }
}

// ---------- exclusive scan of 8192 counts -> gbase, cur ----------
__global__ void k_scan8k(const int* __restrict__ ghist, int* __restrict__ gbase,
                         int* __restrict__ cur) {
    __shared__ int tmp[256];
    int t = threadIdx.x;
    int loc[32];
    int s = 0;
    for (int k = 0; k < 32; ++k) { loc[k] = ghist[t * 32 + k]; s += loc[k]; }
    tmp[t] = s;
    __syncthreads();
    for (int d = 1; d < 256; d <<= 1) {
        int a = (t >= d) ? tmp[t - d] : 0;
        __syncthreads();
        tmp[t] += a;
        __syncthreads();
    }
    int run = tmp[t] - s;
    for (int k = 0; k < 32; ++k) {
        gbase[t * 32 + k] = run;
        cur[t * 32 + k] = run;
        run += loc[k];
    }
}

// ---------- bin edges into bucket/slice staging: (src<<32)|(eid<<9)|dstLocal ----------
__global__ void k_bin(const int* __restrict__ src, const int* __restrict__ dst,
                      int* __restrict__ cur, unsigned long long* __restrict__ stage) {
    int base = blockIdx.x * 2048;
    int c = blockIdx.x & 7;
    int t = threadIdx.x;
    for (int i = t; i < 2048; i += 256) {
        int e = base + i;
        int d = dst[e];
        int b = d >> BSHIFT;
        int pos = atomicAdd(&cur[b * NCOPY + c], 1);
        unsigned long long rec = ((unsigned long long)(unsigned)src[e] << 32)
                               | (unsigned)((e << BSHIFT) | (d & (NPB - 1)));
        stage[pos] = rec;
    }
}

// ---------- per-bucket: deg/dinv + offs + stable csr build (sorted by eid) ----------
__global__ void k_build(const unsigned long long* __restrict__ stage,
                        const int* __restrict__ gbase,
                        float* __restrict__ dinv, int* __restrict__ offs,
                        unsigned long long* __restrict__ csr2) {
    __shared__ int cnt[NPB];
    __shared__ int sstart[NPB];
    __shared__ int tmp[256];
    int b = blockIdx.x, t = threadIdx.x;
    int s0 = gbase[b * NCOPY];
    int s1 = (b == NBUCKET - 1) ? N_EDGES : gbase[(b + 1) * NCOPY];
    for (int j = t; j < NPB; j += 256) cnt[j] = 0;
    __syncthreads();
    for (int i = s0 + t; i < s1; i += 256) {
        unsigned key = (unsigned)stage[i];
        atomicAdd(&cnt[key & (NPB - 1)], 1);
    }
    __syncthreads();
    int j0 = 2 * t, j1 = 2 * t + 1;
    int a0 = cnt[j0], a1 = cnt[j1];
    // dinv = f32(1 / f32(sqrt(deg+1)))  (identical op sequence to reference)
    {
        float d0 = (float)(a0 + 1);
        float q0 = (float)sqrt((double)d0);
        dinv[b * NPB + j0] = (float)(1.0 / (double)q0);
        float d1 = (float)(a1 + 1);
        float q1 = (float)sqrt((double)d1);
        dinv[b * NPB + j1] = (float)(1.0 / (double)q1);
    }
    int s = a0 + a1;
    tmp[t] = s;
    __syncthreads();
    for (int d = 1; d < 256; d <<= 1) {
        int a = (t >= d) ? tmp[t - d] : 0;
        __syncthreads();
        tmp[t] += a;
        __syncthreads();
    }
    int run = tmp[t] - s;
    sstart[j0] = run;
    sstart[j1] = run + a0;
    offs[b * NPB + j0] = s0 + run;
    offs[b * NPB + j1] = s0 + run + a0;
    if (b == NBUCKET - 1 && t == 255) offs[N_NODES] = N_EDGES;
    cnt[j0] = run;          // reuse as scatter cursors
    cnt[j1] = run + a0;
    __syncthreads();
    // scatter into this bucket's csr window (L2-resident)
    for (int i = s0 + t; i < s1; i += 256) {
        unsigned long long v = stage[i];
        int pos = s0 + atomicAdd(&cnt[(unsigned)v & (NPB - 1)], 1);
        csr2[pos] = v;
    }
    __syncthreads();
    // per-node insertion sort by packed key (== eid order within a node)
    for (int jj = 0; jj < 2; ++jj) {
        int j = 2 * t + jj;
        int beg = s0 + sstart[j];
        int end = s0 + cnt[j];   // cnt[j] == sstart[j] + count after scatter
        for (int i = beg + 1; i < end; ++i) {
            unsigned long long v = csr2[i];
            unsigned kv = (unsigned)v;
            int q = i - 1;
            while (q >= beg && (unsigned)csr2[q] > kv) { csr2[q + 1] = csr2[q]; --q; }
            csr2[q + 1] = v;
        }
    }
}

// ---------- rs = f32(1 / f32(sqrt(f32(rvar + 1e-5)))) ----------
__global__ void k_bnprep(const float* __restrict__ rvar, float* __restrict__ rs) {
    int i = threadIdx.x;
    if (i < NLAYERS * HDIM) {
        float rv = __fadd_rn(rvar[i], 1e-5f);
        float sq = (float)sqrt((double)rv);
        rs[i] = (float)(1.0 / (double)sq);
    }
}

// ---------- fused embed + matmul layer0 ----------
__global__ void k_embed_mm(const int* __restrict__ xz, const float* __restrict__ emb,
                           const float* __restrict__ Wc, float* __restrict__ h) {
    __shared__ float Wl[HDIM * HDIM];
    __shared__ float xt[256];
    int t = threadIdx.x;
    int base = blockIdx.x * 256;
    for (int i = t; i < HDIM * HDIM; i += 256) Wl[i] = Wc[i];
    {
        int gid = base + t;
        int n = gid >> 5, c = gid & 31;
        xt[t] = emb[xz[n] * HDIM + c];
    }
    __syncthreads();
    int nl = t >> 5, c = t & 31;
    float acc = 0.0f;
#pragma unroll
    for (int k = 0; k < HDIM; ++k) acc = __fmaf_rn(xt[nl * HDIM + k], Wl[k * HDIM + c], acc);
    h[base + t] = acc;
}

// ---------- agg phase (strict f32 op order) ----------
__device__ __forceinline__ float agg_phase(const float* __restrict__ h,
                                           const float* __restrict__ dinv,
                                           const int* __restrict__ offs,
                                           const unsigned long long* __restrict__ csr2,
                                           const float* __restrict__ bc,
                                           const float* __restrict__ rmean,
                                           const float* __restrict__ rs,
                                           const float* __restrict__ gamma,
                                           const float* __restrict__ beta,
                                           int gid) {
    int n = gid >> 5, c = gid & 31;
    float di = dinv[n];
    float accE = 0.0f;  // np.add.at: sequential in edge-id order
    int beg = offs[n], end = offs[n + 1];
    if (beg < end) {
        int s = (int)(csr2[beg] >> 32);
        float hv = h[s * HDIM + c];
        float dv = dinv[s];
        for (int i = beg + 1; i < end; ++i) {
            int s1 = (int)(csr2[i] >> 32);   // prefetch next edge
            float hv1 = h[s1 * HDIM + c];
            float dv1 = dinv[s1];
            accE = __fadd_rn(accE, __fmul_rn(hv, __fmul_rn(dv, di)));
            hv = hv1; dv = dv1;
        }
        accE = __fadd_rn(accE, __fmul_rn(hv, __fmul_rn(dv, di)));
    }
    float sn = __fmul_rn(di, di);
    float t1 = __fmul_rn(h[gid], sn);
    float a2 = __fadd_rn(accE, t1);
    float a3 = __fadd_rn(a2, bc[c]);
    float tt = __fsub_rn(a3, rmean[c]);
    float u  = __fmul_rn(tt, rs[c]);
    float v  = __fmul_rn(u, gamma[c]);
    float xn = __fadd_rn(v, beta[c]);
    return (xn > 0.0f) ? xn : 0.0f;
}

// ---------- fused agg(BN,ReLU) + next-layer matmul ----------
__global__ void k_agg_mm(const float* __restrict__ h, const float* __restrict__ dinv,
                         const int* __restrict__ offs,
                         const unsigned long long* __restrict__ csr2,
                         const float* __restrict__ bc, const float* __restrict__ rmean,
                         const float* __restrict__ rs, const float* __restrict__ gamma,
                         const float* __restrict__ beta,
                         const float* __restrict__ Wnext, float* __restrict__ hout) {
    __shared__ float Wl[HDIM * HDIM];
    __shared__ float xt[256];
    int t = threadIdx.x;
    int base = blockIdx.x * 256;
    for (int i = t; i < HDIM * HDIM; i += 256) Wl[i] = Wnext[i];
    xt[t] = agg_phase(h, dinv, offs, csr2, bc, rmean, rs, gamma, beta, base + t);
    __syncthreads();
    int nl = t >> 5, c = t & 31;
    float acc = 0.0f;
#pragma unroll
    for (int k = 0; k < HDIM; ++k) acc = __fmaf_rn(xt[nl * HDIM + k], Wl[k * HDIM + c], acc);
    hout[base + t] = acc;
}

// ---------- last agg ----------
__global__ void k_agg_last(const float* __restrict__ h, const float* __restrict__ dinv,
                           const int* __restrict__ offs,
                           const unsigned long long* __restrict__ csr2,
                           const float* __restrict__ bc, const float* __restrict__ rmean,
                           const float* __restrict__ rs, const float* __restrict__ gamma,
                           const float* __restrict__ beta, float* __restrict__ xout) {
    int gid = blockIdx.x * 256 + threadIdx.x;
    xout[gid] = agg_phase(h, dinv, offs, csr2, bc, rmean, rs, gamma, beta, gid);
}

// ---------- per-graph starts ----------
__global__ void k_starts(const int* __restrict__ batch, int* __restrict__ start) {
    int n = blockIdx.x * 256 + threadIdx.x;
    if (n >= N_NODES) return;
    int bn = batch[n];
    int bp = (n == 0) ? -1 : batch[n - 1];
    for (int g = bp + 1; g <= bn; ++g) start[g] = n;
    if (n == N_NODES - 1) {
        for (int g = bn + 1; g <= N_GRAPHS; ++g) start[g] = N_NODES;
    }
}

// ---------- sort-pool (f32 keys, stable) + MLP (f64 accumulate) ----------
__global__ void k_pool_mlp(const float* __restrict__ x, const int* __restrict__ start,
                           const float* __restrict__ W1, const float* __restrict__ b1,
                           const float* __restrict__ W2, const float* __restrict__ b2,
                           const float* __restrict__ W3, const float* __restrict__ b3,
                           float* __restrict__ out) {
    int g = blockIdx.x;
    int t = threadIdx.x;  // 64 threads = 1 wave
    int s = start[g], e = start[g + 1];
    int cnt = e - s;

    __shared__ int sel[KPOOL];
    __shared__ float pl[KPOOL * HDIM];
    __shared__ double part[64];
    __shared__ double h1[HDIM];
    __shared__ double h2[HDIM / 2];

    unsigned long long prev = ~0ull;
    for (int k = 0; k < KPOOL; ++k) {
        if (k < cnt) {
            unsigned long long best = 0ull;
            for (int n = s + t; n < e; n += 64) {
                float v = x[n * HDIM + (HDIM - 1)];
                unsigned long long key =
                    ((unsigned long long)__float_as_uint(v) << 32) | (unsigned int)(~n);
                if (key < prev && key > best) best = key;
            }
            for (int off = 32; off; off >>= 1) {
                unsigned long long o = __shfl_down(best, off);
                if (o > best) best = o;
            }
            best = __shfl(best, 0);
            prev = best;
            if (t == 0) sel[k] = (int)(~((unsigned int)(best & 0xffffffffull)));
        } else {
            if (t == 0) sel[k] = -1;
        }
    }
    __syncthreads();

    for (int idx = t; idx < KPOOL * HDIM; idx += 64) {
        int k = idx >> 5, c = idx & 31;
        int n = sel[k];
        pl[idx] = (n >= 0) ? x[n * HDIM + c] : 0.0f;
    }
    __syncthreads();

    {
        int j = t & 31;
        int half = t >> 5;
        double acc = 0.0;
        int r0 = half * (KPOOL * HDIM / 2);
        for (int r = r0; r < r0 + KPOOL * HDIM / 2; ++r)
            acc += (double)pl[r] * (double)W1[r * HDIM + j];
        part[t] = acc;
    }
    __syncthreads();
    if (t < HDIM) {
        double v = part[t] + part[t + 32] + (double)b1[t];
        h1[t] = (v > 0.0) ? v : 0.0;
    }
    __syncthreads();

    if (t < HDIM / 2) {
        double a2 = (double)b2[t];
        for (int i = 0; i < HDIM; ++i) a2 += h1[i] * (double)W2[i * (HDIM / 2) + t];
        h2[t] = (a2 > 0.0) ? a2 : 0.0;
    }
    __syncthreads();

    if (t == 0) {
        double o = (double)b3[0];
        for (int i = 0; i < HDIM / 2; ++i) o += h2[i] * (double)W3[i];
        out[g] = (float)o;
    }
}

extern "C" void kernel_launch(void* const* d_in, const int* in_sizes, int n_in,
                              void* d_out, int out_size, void* d_ws, size_t ws_size,
                              hipStream_t stream) {
    const int*   xz    = (const int*)d_in[0];
    const int*   src   = (const int*)d_in[1];            // edge_index[0]
    const int*   dst   = (const int*)d_in[1] + N_EDGES;  // edge_index[1]
    const int*   batch = (const int*)d_in[2];
    const float* emb   = (const float*)d_in[3];
    const float* Wc    = (const float*)d_in[4];
    const float* bc    = (const float*)d_in[5];
    const float* gamma = (const float*)d_in[6];
    const float* beta  = (const float*)d_in[7];
    const float* rmean = (const float*)d_in[8];
    const float* rvar  = (const float*)d_in[9];
    const float* W1    = (const float*)d_in[10];
    const float* b1    = (const float*)d_in[11];
    const float* W2    = (const float*)d_in[12];
    const float* b2    = (const float*)d_in[13];
    const float* W3    = (const float*)d_in[14];
    const float* b3    = (const float*)d_in[15];
    float* out = (float*)d_out;

    // workspace carve-up (256B aligned). Total ~206 MB.
    char* p = (char*)d_ws;
    auto carve = [&](size_t bytes) {
        void* q = (void*)p;
        p += (bytes + 255) & ~size_t(255);
        return q;
    };
    int*   ghist = (int*)carve(HIST_SZ * 4);
    int*   gbase = (int*)carve(HIST_SZ * 4);
    int*   cur   = (int*)carve(HIST_SZ * 4);
    unsigned long long* stage = (unsigned long long*)carve((size_t)N_EDGES * 8);
    unsigned long long* csr2  = (unsigned long long*)carve((size_t)N_EDGES * 8);
    float* dinv  = (float*)carve(N_NODES * 4);
    int*   offs  = (int*)carve((N_NODES + 1) * 4);
    int*   start = (int*)carve((N_GRAPHS + 1) * 4);
    float* rs    = (float*)carve(NLAYERS * HDIM * 4);
    float* bufA  = (float*)carve((size_t)N_NODES * HDIM * 4);
    float* bufB  = (float*)carve((size_t)N_NODES * HDIM * 4);

    hipMemsetAsync(ghist, 0, HIST_SZ * 4, stream);

    k_hist<<<N_EDGES / 2048, 256, 0, stream>>>(dst, ghist);
    k_scan8k<<<1, 256, 0, stream>>>(ghist, gbase, cur);
    k_bin<<<N_EDGES / 2048, 256, 0, stream>>>(src, dst, cur, stage);
    k_build<<<NBUCKET, 256, 0, stream>>>(stage, gbase, dinv, offs, csr2);
    k_bnprep<<<1, 128, 0, stream>>>(rvar, rs);
    k_starts<<<N_NODES / 256, 256, 0, stream>>>(batch, start);

    const int NG = (N_NODES * HDIM) / 256;
    k_embed_mm<<<NG, 256, 0, stream>>>(xz, emb, Wc + 0 * HDIM * HDIM, bufA);
    k_agg_mm<<<NG, 256, 0, stream>>>(bufA, dinv, offs, csr2,
        bc + 0 * HDIM, rmean + 0 * HDIM, rs + 0 * HDIM, gamma + 0 * HDIM, beta + 0 * HDIM,
        Wc + 1 * HDIM * HDIM, bufB);
    k_agg_mm<<<NG, 256, 0, stream>>>(bufB, dinv, offs, csr2,
        bc + 1 * HDIM, rmean + 1 * HDIM, rs + 1 * HDIM, gamma + 1 * HDIM, beta + 1 * HDIM,
        Wc + 2 * HDIM * HDIM, bufA);
    k_agg_last<<<NG, 256, 0, stream>>>(bufA, dinv, offs, csr2,
        bc + 2 * HDIM, rmean + 2 * HDIM, rs + 2 * HDIM, gamma + 2 * HDIM, beta + 2 * HDIM,
        bufB);

    k_pool_mlp<<<N_GRAPHS, 64, 0, stream>>>(bufB, start, W1, b1, W2, b2, W3, b3, out);
}

// Round 7
// 1442.413 us; speedup vs baseline: 1.6428x; 1.2302x over previous
//
#include <hip/hip_runtime.h>
#include <hip/hip_bf16.h>
#include <stdint.h>

#define N_NODES 524288
#define N_EDGES 4194304
#define N_GRAPHS 4096
#define HDIM 32
#define NLAYERS 3
#define KPOOL 30

#define NBUCKET 1024
#define BSHIFT 9             // bucket = dst >> 9
#define NPB 512              // nodes per bucket
#define NCOPY 8              // per-XCD slice copies
#define HIST_SZ (NBUCKET * NCOPY)

// ---------- histogram of edges per (bucket, xcd-slice) ----------
__global__ void k_hist(const int* __restrict__ dst, int* __restrict__ ghist) {
    __shared__ int lh[NBUCKET];
    int t = threadIdx.x;
    for (int i = t; i < NBUCKET; i += 256) lh[i] = 0;
    __syncthreads();
    int base = blockIdx.x * 2048;
    for (int i = t; i < 2048; i += 256) {
        int d = dst[base + i];
        atomicAdd(&lh[d >> BSHIFT], 1);
    }
    __syncthreads();
    int c = blockIdx.x & 7;
    for (int i = t; i < NBUCKET; i += 256) {
        int v = lh[i];
        if (v) atomicAdd(&ghist[i * NCOPY + c], v);
    }
}

// ---------- exclusive scan of 8192 counts -> gbase, cur ----------
__global__ void k_scan8k(const int* __restrict__ ghist, int* __restrict__ gbase,
                         int* __restrict__ cur) {
    __shared__ int tmp[256];
    int t = threadIdx.x;
    int loc[32];
    int s = 0;
    for (int k = 0; k < 32; ++k) { loc[k] = ghist[t * 32 + k]; s += loc[k]; }
    tmp[t] = s;
    __syncthreads();
    for (int d = 1; d < 256; d <<= 1) {
        int a = (t >= d) ? tmp[t - d] : 0;
        __syncthreads();
        tmp[t] += a;
        __syncthreads();
    }
    int run = tmp[t] - s;
    for (int k = 0; k < 32; ++k) {
        gbase[t * 32 + k] = run;
        cur[t * 32 + k] = run;
        run += loc[k];
    }
}

// ---------- bin edges into bucket/slice staging: (src<<32)|(eid<<9)|dstLocal ----------
__global__ void k_bin(const int* __restrict__ src, const int* __restrict__ dst,
                      int* __restrict__ cur, unsigned long long* __restrict__ stage) {
    int base = blockIdx.x * 2048;
    int c = blockIdx.x & 7;
    int t = threadIdx.x;
    for (int i = t; i < 2048; i += 256) {
        int e = base + i;
        int d = dst[e];
        int b = d >> BSHIFT;
        int pos = atomicAdd(&cur[b * NCOPY + c], 1);
        unsigned long long rec = ((unsigned long long)(unsigned)src[e] << 32)
                               | (unsigned)((e << BSHIFT) | (d & (NPB - 1)));
        stage[pos] = rec;
    }
}

// ---------- per-bucket: deg/dinv + offs + stable csr build (sorted by eid) ----------
__global__ void k_build(const unsigned long long* __restrict__ stage,
                        const int* __restrict__ gbase,
                        float* __restrict__ dinv, int* __restrict__ offs,
                        unsigned long long* __restrict__ csr2) {
    __shared__ int cnt[NPB];
    __shared__ int sstart[NPB];
    __shared__ int tmp[256];
    int b = blockIdx.x, t = threadIdx.x;
    int s0 = gbase[b * NCOPY];
    int s1 = (b == NBUCKET - 1) ? N_EDGES : gbase[(b + 1) * NCOPY];
    for (int j = t; j < NPB; j += 256) cnt[j] = 0;
    __syncthreads();
    for (int i = s0 + t; i < s1; i += 256) {
        unsigned key = (unsigned)stage[i];
        atomicAdd(&cnt[key & (NPB - 1)], 1);
    }
    __syncthreads();
    int j0 = 2 * t, j1 = 2 * t + 1;
    int a0 = cnt[j0], a1 = cnt[j1];
    // dinv = f32(1 / f32(sqrt(deg+1)))  (identical op sequence to reference)
    {
        float d0 = (float)(a0 + 1);
        float q0 = (float)sqrt((double)d0);
        dinv[b * NPB + j0] = (float)(1.0 / (double)q0);
        float d1 = (float)(a1 + 1);
        float q1 = (float)sqrt((double)d1);
        dinv[b * NPB + j1] = (float)(1.0 / (double)q1);
    }
    int s = a0 + a1;
    tmp[t] = s;
    __syncthreads();
    for (int d = 1; d < 256; d <<= 1) {
        int a = (t >= d) ? tmp[t - d] : 0;
        __syncthreads();
        tmp[t] += a;
        __syncthreads();
    }
    int run = tmp[t] - s;
    sstart[j0] = run;
    sstart[j1] = run + a0;
    offs[b * NPB + j0] = s0 + run;
    offs[b * NPB + j1] = s0 + run + a0;
    if (b == NBUCKET - 1 && t == 255) offs[N_NODES] = N_EDGES;
    cnt[j0] = run;          // reuse as scatter cursors
    cnt[j1] = run + a0;
    __syncthreads();
    // scatter into this bucket's csr window (L2-resident)
    for (int i = s0 + t; i < s1; i += 256) {
        unsigned long long v = stage[i];
        int pos = s0 + atomicAdd(&cnt[(unsigned)v & (NPB - 1)], 1);
        csr2[pos] = v;
    }
    __syncthreads();
    // per-node insertion sort by packed key (== eid order within a node)
    for (int jj = 0; jj < 2; ++jj) {
        int j = 2 * t + jj;
        int beg = s0 + sstart[j];
        int end = s0 + cnt[j];   // cnt[j] == sstart[j] + count after scatter
        for (int i = beg + 1; i < end; ++i) {
            unsigned long long v = csr2[i];
            unsigned kv = (unsigned)v;
            int q = i - 1;
            while (q >= beg && (unsigned)csr2[q] > kv) { csr2[q + 1] = csr2[q]; --q; }
            csr2[q + 1] = v;
        }
    }
}

// ---------- pack dinv[src] into the (now dead) low word of each record ----------
__global__ void k_pack(const float* __restrict__ dinv, unsigned long long* __restrict__ csr2) {
    int i = blockIdx.x * 256 + threadIdx.x;
    if (i < N_EDGES) {
        unsigned long long r = csr2[i];
        int s = (int)(r >> 32);
        csr2[i] = (r & 0xffffffff00000000ull) | (unsigned)__float_as_uint(dinv[s]);
    }
}

// ---------- rs = f32(1 / f32(sqrt(f32(rvar + 1e-5)))) ----------
__global__ void k_bnprep(const float* __restrict__ rvar, float* __restrict__ rs) {
    int i = threadIdx.x;
    if (i < NLAYERS * HDIM) {
        float rv = __fadd_rn(rvar[i], 1e-5f);
        float sq = (float)sqrt((double)rv);
        rs[i] = (float)(1.0 / (double)sq);
    }
}

// ---------- fused embed + matmul layer0 ----------
__global__ void k_embed_mm(const int* __restrict__ xz, const float* __restrict__ emb,
                           const float* __restrict__ Wc, float* __restrict__ h) {
    __shared__ float Wl[HDIM * HDIM];
    __shared__ float xt[256];
    int t = threadIdx.x;
    int base = blockIdx.x * 256;
    for (int i = t; i < HDIM * HDIM; i += 256) Wl[i] = Wc[i];
    {
        int gid = base + t;
        int n = gid >> 5, c = gid & 31;
        xt[t] = emb[xz[n] * HDIM + c];
    }
    __syncthreads();
    int nl = t >> 5, c = t & 31;
    float acc = 0.0f;
#pragma unroll
    for (int k = 0; k < HDIM; ++k) acc = __fmaf_rn(xt[nl * HDIM + k], Wl[k * HDIM + c], acc);
    h[base + t] = acc;
}

// ---------- agg phase: strict f32 op order, 4-deep software pipeline ----------
__device__ __forceinline__ float agg_phase(const float* __restrict__ h,
                                           const float* __restrict__ dinv,
                                           const int* __restrict__ offs,
                                           const unsigned long long* __restrict__ csr2,
                                           const float* __restrict__ bc,
                                           const float* __restrict__ rmean,
                                           const float* __restrict__ rs,
                                           const float* __restrict__ gamma,
                                           const float* __restrict__ beta,
                                           int gid) {
    int n = gid >> 5, c = gid & 31;
    float di = dinv[n];
    float accE = 0.0f;  // np.add.at: sequential in edge-id order
    int beg = offs[n], end = offs[n + 1];
    int i = beg;
    // 4-wide chunks: 4 independent record loads -> 4 independent h-row gathers,
    // then the 4 ordered adds. Order of __fadd_rn is untouched (eid order).
    for (; i + 4 <= end; i += 4) {
        unsigned long long r0 = csr2[i];
        unsigned long long r1 = csr2[i + 1];
        unsigned long long r2 = csr2[i + 2];
        unsigned long long r3 = csr2[i + 3];
        float h0 = h[(int)(r0 >> 32) * HDIM + c];
        float h1 = h[(int)(r1 >> 32) * HDIM + c];
        float h2 = h[(int)(r2 >> 32) * HDIM + c];
        float h3 = h[(int)(r3 >> 32) * HDIM + c];
        float d0 = __uint_as_float((unsigned)r0);
        float d1 = __uint_as_float((unsigned)r1);
        float d2 = __uint_as_float((unsigned)r2);
        float d3 = __uint_as_float((unsigned)r3);
        accE = __fadd_rn(accE, __fmul_rn(h0, __fmul_rn(d0, di)));
        accE = __fadd_rn(accE, __fmul_rn(h1, __fmul_rn(d1, di)));
        accE = __fadd_rn(accE, __fmul_rn(h2, __fmul_rn(d2, di)));
        accE = __fadd_rn(accE, __fmul_rn(h3, __fmul_rn(d3, di)));
    }
    for (; i < end; ++i) {
        unsigned long long r = csr2[i];
        float hv = h[(int)(r >> 32) * HDIM + c];
        float dv = __uint_as_float((unsigned)r);
        accE = __fadd_rn(accE, __fmul_rn(hv, __fmul_rn(dv, di)));
    }
    float sn = __fmul_rn(di, di);
    float t1 = __fmul_rn(h[gid], sn);
    float a2 = __fadd_rn(accE, t1);
    float a3 = __fadd_rn(a2, bc[c]);
    float tt = __fsub_rn(a3, rmean[c]);
    float u  = __fmul_rn(tt, rs[c]);
    float v  = __fmul_rn(u, gamma[c]);
    float xn = __fadd_rn(v, beta[c]);
    return (xn > 0.0f) ? xn : 0.0f;
}

// ---------- fused agg(BN,ReLU) + next-layer matmul ----------
__global__ void k_agg_mm(const float* __restrict__ h, const float* __restrict__ dinv,
                         const int* __restrict__ offs,
                         const unsigned long long* __restrict__ csr2,
                         const float* __restrict__ bc, const float* __restrict__ rmean,
                         const float* __restrict__ rs, const float* __restrict__ gamma,
                         const float* __restrict__ beta,
                         const float* __restrict__ Wnext, float* __restrict__ hout) {
    __shared__ float Wl[HDIM * HDIM];
    __shared__ float xt[256];
    int t = threadIdx.x;
    int base = blockIdx.x * 256;
    for (int i = t; i < HDIM * HDIM; i += 256) Wl[i] = Wnext[i];
    xt[t] = agg_phase(h, dinv, offs, csr2, bc, rmean, rs, gamma, beta, base + t);
    __syncthreads();
    int nl = t >> 5, c = t & 31;
    float acc = 0.0f;
#pragma unroll
    for (int k = 0; k < HDIM; ++k) acc = __fmaf_rn(xt[nl * HDIM + k], Wl[k * HDIM + c], acc);
    hout[base + t] = acc;
}

// ---------- last agg ----------
__global__ void k_agg_last(const float* __restrict__ h, const float* __restrict__ dinv,
                           const int* __restrict__ offs,
                           const unsigned long long* __restrict__ csr2,
                           const float* __restrict__ bc, const float* __restrict__ rmean,
                           const float* __restrict__ rs, const float* __restrict__ gamma,
                           const float* __restrict__ beta, float* __restrict__ xout) {
    int gid = blockIdx.x * 256 + threadIdx.x;
    xout[gid] = agg_phase(h, dinv, offs, csr2, bc, rmean, rs, gamma, beta, gid);
}

// ---------- per-graph starts ----------
__global__ void k_starts(const int* __restrict__ batch, int* __restrict__ start) {
    int n = blockIdx.x * 256 + threadIdx.x;
    if (n >= N_NODES) return;
    int bn = batch[n];
    int bp = (n == 0) ? -1 : batch[n - 1];
    for (int g = bp + 1; g <= bn; ++g) start[g] = n;
    if (n == N_NODES - 1) {
        for (int g = bn + 1; g <= N_GRAPHS; ++g) start[g] = N_NODES;
    }
}

// ---------- sort-pool (f32 keys, stable) + MLP (f64 accumulate) ----------
__global__ void k_pool_mlp(const float* __restrict__ x, const int* __restrict__ start,
                           const float* __restrict__ W1, const float* __restrict__ b1,
                           const float* __restrict__ W2, const float* __restrict__ b2,
                           const float* __restrict__ W3, const float* __restrict__ b3,
                           float* __restrict__ out) {
    int g = blockIdx.x;
    int t = threadIdx.x;  // 64 threads = 1 wave
    int s = start[g], e = start[g + 1];
    int cnt = e - s;

    __shared__ int sel[KPOOL];
    __shared__ float pl[KPOOL * HDIM];
    __shared__ double part[64];
    __shared__ double h1[HDIM];
    __shared__ double h2[HDIM / 2];

    unsigned long long prev = ~0ull;
    for (int k = 0; k < KPOOL; ++k) {
        if (k < cnt) {
            unsigned long long best = 0ull;
            for (int n = s + t; n < e; n += 64) {
                float v = x[n * HDIM + (HDIM - 1)];
                unsigned long long key =
                    ((unsigned long long)__float_as_uint(v) << 32) | (unsigned int)(~n);
                if (key < prev && key > best) best = key;
            }
            for (int off = 32; off; off >>= 1) {
                unsigned long long o = __shfl_down(best, off);
                if (o > best) best = o;
            }
            best = __shfl(best, 0);
            prev = best;
            if (t == 0) sel[k] = (int)(~((unsigned int)(best & 0xffffffffull)));
        } else {
            if (t == 0) sel[k] = -1;
        }
    }
    __syncthreads();

    for (int idx = t; idx < KPOOL * HDIM; idx += 64) {
        int k = idx >> 5, c = idx & 31;
        int n = sel[k];
        pl[idx] = (n >= 0) ? x[n * HDIM + c] : 0.0f;
    }
    __syncthreads();

    {
        int j = t & 31;
        int half = t >> 5;
        double acc = 0.0;
        int r0 = half * (KPOOL * HDIM / 2);
        for (int r = r0; r < r0 + KPOOL * HDIM / 2; ++r)
            acc += (double)pl[r] * (double)W1[r * HDIM + j];
        part[t] = acc;
    }
    __syncthreads();
    if (t < HDIM) {
        double v = part[t] + part[t + 32] + (double)b1[t];
        h1[t] = (v > 0.0) ? v : 0.0;
    }
    __syncthreads();

    if (t < HDIM / 2) {
        double a2 = (double)b2[t];
        for (int i = 0; i < HDIM; ++i) a2 += h1[i] * (double)W2[i * (HDIM / 2) + t];
        h2[t] = (a2 > 0.0) ? a2 : 0.0;
    }
    __syncthreads();

    if (t == 0) {
        double o = (double)b3[0];
        for (int i = 0; i < HDIM / 2; ++i) o += h2[i] * (double)W3[i];
        out[g] = (float)o;
    }
}

extern "C" void kernel_launch(void* const* d_in, const int* in_sizes, int n_in,
                              void* d_out, int out_size, void* d_ws, size_t ws_size,
                              hipStream_t stream) {
    const int*   xz    = (const int*)d_in[0];
    const int*   src   = (const int*)d_in[1];            // edge_index[0]
    const int*   dst   = (const int*)d_in[1] + N_EDGES;  // edge_index[1]
    const int*   batch = (const int*)d_in[2];
    const float* emb   = (const float*)d_in[3];
    const float* Wc    = (const float*)d_in[4];
    const float* bc    = (const float*)d_in[5];
    const float* gamma = (const float*)d_in[6];
    const float* beta  = (const float*)d_in[7];
    const float* rmean = (const float*)d_in[8];
    const float* rvar  = (const float*)d_in[9];
    const float* W1    = (const float*)d_in[10];
    const float* b1    = (const float*)d_in[11];
    const float* W2    = (const float*)d_in[12];
    const float* b2    = (const float*)d_in[13];
    const float* W3    = (const float*)d_in[14];
    const float* b3    = (const float*)d_in[15];
    float* out = (float*)d_out;

    // workspace carve-up (256B aligned). Total ~206 MB.
    char* p = (char*)d_ws;
    auto carve = [&](size_t bytes) {
        void* q = (void*)p;
        p += (bytes + 255) & ~size_t(255);
        return q;
    };
    int*   ghist = (int*)carve(HIST_SZ * 4);
    int*   gbase = (int*)carve(HIST_SZ * 4);
    int*   cur   = (int*)carve(HIST_SZ * 4);
    unsigned long long* stage = (unsigned long long*)carve((size_t)N_EDGES * 8);
    unsigned long long* csr2  = (unsigned long long*)carve((size_t)N_EDGES * 8);
    float* dinv  = (float*)carve(N_NODES * 4);
    int*   offs  = (int*)carve((N_NODES + 1) * 4);
    int*   start = (int*)carve((N_GRAPHS + 1) * 4);
    float* rs    = (float*)carve(NLAYERS * HDIM * 4);
    float* bufA  = (float*)carve((size_t)N_NODES * HDIM * 4);
    float* bufB  = (float*)carve((size_t)N_NODES * HDIM * 4);

    hipMemsetAsync(ghist, 0, HIST_SZ * 4, stream);

    k_hist<<<N_EDGES / 2048, 256, 0, stream>>>(dst, ghist);
    k_scan8k<<<1, 256, 0, stream>>>(ghist, gbase, cur);
    k_bin<<<N_EDGES / 2048, 256, 0, stream>>>(src, dst, cur, stage);
    k_build<<<NBUCKET, 256, 0, stream>>>(stage, gbase, dinv, offs, csr2);
    k_pack<<<N_EDGES / 256, 256, 0, stream>>>(dinv, csr2);
    k_bnprep<<<1, 128, 0, stream>>>(rvar, rs);
    k_starts<<<N_NODES / 256, 256, 0, stream>>>(batch, start);

    const int NG = (N_NODES * HDIM) / 256;
    k_embed_mm<<<NG, 256, 0, stream>>>(xz, emb, Wc + 0 * HDIM * HDIM, bufA);
    k_agg_mm<<<NG, 256, 0, stream>>>(bufA, dinv, offs, csr2,
        bc + 0 * HDIM, rmean + 0 * HDIM, rs + 0 * HDIM, gamma + 0 * HDIM, beta + 0 * HDIM,
        Wc + 1 * HDIM * HDIM, bufB);
    k_agg_mm<<<NG, 256, 0, stream>>>(bufB, dinv, offs, csr2,
        bc + 1 * HDIM, rmean + 1 * HDIM, rs + 1 * HDIM, gamma + 1 * HDIM, beta + 1 * HDIM,
        Wc + 2 * HDIM * HDIM, bufA);
    k_agg_last<<<NG, 256, 0, stream>>>(bufA, dinv, offs, csr2,
        bc + 2 * HDIM, rmean + 2 * HDIM, rs + 2 * HDIM, gamma + 2 * HDIM, beta + 2 * HDIM,
        bufB);

    k_pool_mlp<<<N_GRAPHS, 64, 0, stream>>>(bufB, start, W1, b1, W2, b2, W3, b3, out);
}

// Round 8
// 1228.362 us; speedup vs baseline: 1.9291x; 1.1743x over previous
//
#include <hip/hip_runtime.h>
#include <hip/hip_bf16.h>
#include <stdint.h>

#define N_NODES 524288
#define N_EDGES 4194304
#define N_GRAPHS 4096
#define HDIM 32
#define NLAYERS 3
#define KPOOL 30
#define MAXC 1024            // max nodes/graph handled in-LDS (avg 128; overflow -> fallback)

#define NBUCKET 1024
#define BSHIFT 9             // bucket = dst >> 9
#define NPB 512              // nodes per bucket
#define NCOPY 8              // per-XCD slice copies
#define HIST_SZ (NBUCKET * NCOPY)

// ---------- histogram of edges per (bucket, xcd-slice) ----------
__global__ void k_hist(const int* __restrict__ dst, int* __restrict__ ghist) {
    __shared__ int lh[NBUCKET];
    int t = threadIdx.x;
    for (int i = t; i < NBUCKET; i += 256) lh[i] = 0;
    __syncthreads();
    int base = blockIdx.x * 2048;
    for (int i = t; i < 2048; i += 256) {
        int d = dst[base + i];
        atomicAdd(&lh[d >> BSHIFT], 1);
    }
    __syncthreads();
    int c = blockIdx.x & 7;
    for (int i = t; i < NBUCKET; i += 256) {
        int v = lh[i];
        if (v) atomicAdd(&ghist[i * NCOPY + c], v);
    }
}

// ---------- exclusive scan of 8192 counts -> gbase, cur ----------
__global__ void k_scan8k(const int* __restrict__ ghist, int* __restrict__ gbase,
                         int* __restrict__ cur) {
    __shared__ int tmp[256];
    int t = threadIdx.x;
    int loc[32];
    int s = 0;
    for (int k = 0; k < 32; ++k) { loc[k] = ghist[t * 32 + k]; s += loc[k]; }
    tmp[t] = s;
    __syncthreads();
    for (int d = 1; d < 256; d <<= 1) {
        int a = (t >= d) ? tmp[t - d] : 0;
        __syncthreads();
        tmp[t] += a;
        __syncthreads();
    }
    int run = tmp[t] - s;
    for (int k = 0; k < 32; ++k) {
        gbase[t * 32 + k] = run;
        cur[t * 32 + k] = run;
        run += loc[k];
    }
}

// ---------- bin edges into bucket/slice staging: (src<<32)|(eid<<9)|dstLocal ----------
__global__ void k_bin(const int* __restrict__ src, const int* __restrict__ dst,
                      int* __restrict__ cur, unsigned long long* __restrict__ stage) {
    int base = blockIdx.x * 2048;
    int c = blockIdx.x & 7;
    int t = threadIdx.x;
    for (int i = t; i < 2048; i += 256) {
        int e = base + i;
        int d = dst[e];
        int b = d >> BSHIFT;
        int pos = atomicAdd(&cur[b * NCOPY + c], 1);
        unsigned long long rec = ((unsigned long long)(unsigned)src[e] << 32)
                               | (unsigned)((e << BSHIFT) | (d & (NPB - 1)));
        stage[pos] = rec;
    }
}

// ---------- per-bucket: deg/dinv + offs + stable csr build (sorted by eid) ----------
__global__ void k_build(const unsigned long long* __restrict__ stage,
                        const int* __restrict__ gbase,
                        float* __restrict__ dinv, int* __restrict__ offs,
                        unsigned long long* __restrict__ csr2) {
    __shared__ int cnt[NPB];
    __shared__ int sstart[NPB];
    __shared__ int tmp[256];
    int b = blockIdx.x, t = threadIdx.x;
    int s0 = gbase[b * NCOPY];
    int s1 = (b == NBUCKET - 1) ? N_EDGES : gbase[(b + 1) * NCOPY];
    for (int j = t; j < NPB; j += 256) cnt[j] = 0;
    __syncthreads();
    for (int i = s0 + t; i < s1; i += 256) {
        unsigned key = (unsigned)stage[i];
        atomicAdd(&cnt[key & (NPB - 1)], 1);
    }
    __syncthreads();
    int j0 = 2 * t, j1 = 2 * t + 1;
    int a0 = cnt[j0], a1 = cnt[j1];
    // dinv = f32(1 / f32(sqrt(deg+1)))  (identical op sequence to reference)
    {
        float d0 = (float)(a0 + 1);
        float q0 = (float)sqrt((double)d0);
        dinv[b * NPB + j0] = (float)(1.0 / (double)q0);
        float d1 = (float)(a1 + 1);
        float q1 = (float)sqrt((double)d1);
        dinv[b * NPB + j1] = (float)(1.0 / (double)q1);
    }
    int s = a0 + a1;
    tmp[t] = s;
    __syncthreads();
    for (int d = 1; d < 256; d <<= 1) {
        int a = (t >= d) ? tmp[t - d] : 0;
        __syncthreads();
        tmp[t] += a;
        __syncthreads();
    }
    int run = tmp[t] - s;
    sstart[j0] = run;
    sstart[j1] = run + a0;
    offs[b * NPB + j0] = s0 + run;
    offs[b * NPB + j1] = s0 + run + a0;
    if (b == NBUCKET - 1 && t == 255) offs[N_NODES] = N_EDGES;
    cnt[j0] = run;          // reuse as scatter cursors
    cnt[j1] = run + a0;
    __syncthreads();
    // scatter into this bucket's csr window (L2-resident)
    for (int i = s0 + t; i < s1; i += 256) {
        unsigned long long v = stage[i];
        int pos = s0 + atomicAdd(&cnt[(unsigned)v & (NPB - 1)], 1);
        csr2[pos] = v;
    }
    __syncthreads();
    // per-node insertion sort by packed key (== eid order within a node)
    for (int jj = 0; jj < 2; ++jj) {
        int j = 2 * t + jj;
        int beg = s0 + sstart[j];
        int end = s0 + cnt[j];
        for (int i = beg + 1; i < end; ++i) {
            unsigned long long v = csr2[i];
            unsigned kv = (unsigned)v;
            int q = i - 1;
            while (q >= beg && (unsigned)csr2[q] > kv) { csr2[q + 1] = csr2[q]; --q; }
            csr2[q + 1] = v;
        }
    }
}

// ---------- pack dinv[src] into the (now dead) low word of each record ----------
__global__ void k_pack(const float* __restrict__ dinv, unsigned long long* __restrict__ csr2) {
    int i = blockIdx.x * 256 + threadIdx.x;
    if (i < N_EDGES) {
        unsigned long long r = csr2[i];
        int s = (int)(r >> 32);
        csr2[i] = (r & 0xffffffff00000000ull) | (unsigned)__float_as_uint(dinv[s]);
    }
}

// ---------- rs = f32(1 / f32(sqrt(f32(rvar + 1e-5)))) ----------
__global__ void k_bnprep(const float* __restrict__ rvar, float* __restrict__ rs) {
    int i = threadIdx.x;
    if (i < NLAYERS * HDIM) {
        float rv = __fadd_rn(rvar[i], 1e-5f);
        float sq = (float)sqrt((double)rv);
        rs[i] = (float)(1.0 / (double)sq);
    }
}

// ---------- fused embed + matmul layer0 ----------
__global__ void k_embed_mm(const int* __restrict__ xz, const float* __restrict__ emb,
                           const float* __restrict__ Wc, float* __restrict__ h) {
    __shared__ float Wl[HDIM * HDIM];
    __shared__ float xt[256];
    int t = threadIdx.x;
    int base = blockIdx.x * 256;
    for (int i = t; i < HDIM * HDIM; i += 256) Wl[i] = Wc[i];
    {
        int gid = base + t;
        int n = gid >> 5, c = gid & 31;
        xt[t] = emb[xz[n] * HDIM + c];
    }
    __syncthreads();
    int nl = t >> 5, c = t & 31;
    float acc = 0.0f;
#pragma unroll
    for (int k = 0; k < HDIM; ++k) acc = __fmaf_rn(xt[nl * HDIM + k], Wl[k * HDIM + c], acc);
    h[base + t] = acc;
}

// ---------- agg phase: strict f32 op order, 4-deep software pipeline ----------
__device__ __forceinline__ float agg_phase(const float* __restrict__ h,
                                           const float* __restrict__ dinv,
                                           const int* __restrict__ offs,
                                           const unsigned long long* __restrict__ csr2,
                                           const float* __restrict__ bc,
                                           const float* __restrict__ rmean,
                                           const float* __restrict__ rs,
                                           const float* __restrict__ gamma,
                                           const float* __restrict__ beta,
                                           int gid) {
    int n = gid >> 5, c = gid & 31;
    float di = dinv[n];
    float accE = 0.0f;  // np.add.at: sequential in edge-id order
    int beg = offs[n], end = offs[n + 1];
    int i = beg;
    for (; i + 4 <= end; i += 4) {
        unsigned long long r0 = csr2[i];
        unsigned long long r1 = csr2[i + 1];
        unsigned long long r2 = csr2[i + 2];
        unsigned long long r3 = csr2[i + 3];
        float h0 = h[(int)(r0 >> 32) * HDIM + c];
        float h1 = h[(int)(r1 >> 32) * HDIM + c];
        float h2 = h[(int)(r2 >> 32) * HDIM + c];
        float h3 = h[(int)(r3 >> 32) * HDIM + c];
        float d0 = __uint_as_float((unsigned)r0);
        float d1 = __uint_as_float((unsigned)r1);
        float d2 = __uint_as_float((unsigned)r2);
        float d3 = __uint_as_float((unsigned)r3);
        accE = __fadd_rn(accE, __fmul_rn(h0, __fmul_rn(d0, di)));
        accE = __fadd_rn(accE, __fmul_rn(h1, __fmul_rn(d1, di)));
        accE = __fadd_rn(accE, __fmul_rn(h2, __fmul_rn(d2, di)));
        accE = __fadd_rn(accE, __fmul_rn(h3, __fmul_rn(d3, di)));
    }
    for (; i < end; ++i) {
        unsigned long long r = csr2[i];
        float hv = h[(int)(r >> 32) * HDIM + c];
        float dv = __uint_as_float((unsigned)r);
        accE = __fadd_rn(accE, __fmul_rn(hv, __fmul_rn(dv, di)));
    }
    float sn = __fmul_rn(di, di);
    float t1 = __fmul_rn(h[gid], sn);
    float a2 = __fadd_rn(accE, t1);
    float a3 = __fadd_rn(a2, bc[c]);
    float tt = __fsub_rn(a3, rmean[c]);
    float u  = __fmul_rn(tt, rs[c]);
    float v  = __fmul_rn(u, gamma[c]);
    float xn = __fadd_rn(v, beta[c]);
    return (xn > 0.0f) ? xn : 0.0f;
}

// ---------- fused agg(BN,ReLU) + next-layer matmul ----------
__global__ void k_agg_mm(const float* __restrict__ h, const float* __restrict__ dinv,
                         const int* __restrict__ offs,
                         const unsigned long long* __restrict__ csr2,
                         const float* __restrict__ bc, const float* __restrict__ rmean,
                         const float* __restrict__ rs, const float* __restrict__ gamma,
                         const float* __restrict__ beta,
                         const float* __restrict__ Wnext, float* __restrict__ hout) {
    __shared__ float Wl[HDIM * HDIM];
    __shared__ float xt[256];
    int t = threadIdx.x;
    int base = blockIdx.x * 256;
    for (int i = t; i < HDIM * HDIM; i += 256) Wl[i] = Wnext[i];
    xt[t] = agg_phase(h, dinv, offs, csr2, bc, rmean, rs, gamma, beta, base + t);
    __syncthreads();
    int nl = t >> 5, c = t & 31;
    float acc = 0.0f;
#pragma unroll
    for (int k = 0; k < HDIM; ++k) acc = __fmaf_rn(xt[nl * HDIM + k], Wl[k * HDIM + c], acc);
    hout[base + t] = acc;
}

// ---------- last agg: also emit dense channel-31 array for the sort-pool ----------
__global__ void k_agg_last(const float* __restrict__ h, const float* __restrict__ dinv,
                           const int* __restrict__ offs,
                           const unsigned long long* __restrict__ csr2,
                           const float* __restrict__ bc, const float* __restrict__ rmean,
                           const float* __restrict__ rs, const float* __restrict__ gamma,
                           const float* __restrict__ beta, float* __restrict__ xout,
                           float* __restrict__ lastc) {
    int gid = blockIdx.x * 256 + threadIdx.x;
    float v = agg_phase(h, dinv, offs, csr2, bc, rmean, rs, gamma, beta, gid);
    xout[gid] = v;
    if ((gid & 31) == 31) lastc[gid >> 5] = v;
}

// ---------- per-graph starts ----------
__global__ void k_starts(const int* __restrict__ batch, int* __restrict__ start) {
    int n = blockIdx.x * 256 + threadIdx.x;
    if (n >= N_NODES) return;
    int bn = batch[n];
    int bp = (n == 0) ? -1 : batch[n - 1];
    for (int g = bp + 1; g <= bn; ++g) start[g] = n;
    if (n == N_NODES - 1) {
        for (int g = bn + 1; g <= N_GRAPHS; ++g) start[g] = N_NODES;
    }
}

// ---------- sort-pool (keys cached in LDS) + MLP (f64 accumulate) ----------
__global__ void k_pool_mlp(const float* __restrict__ x, const float* __restrict__ lastc,
                           const int* __restrict__ start,
                           const float* __restrict__ W1, const float* __restrict__ b1,
                           const float* __restrict__ W2, const float* __restrict__ b2,
                           const float* __restrict__ W3, const float* __restrict__ b3,
                           float* __restrict__ out) {
    int g = blockIdx.x;
    int t = threadIdx.x;  // 64 threads = 1 wave
    int s = start[g], e = start[g + 1];
    int cnt = e - s;

    __shared__ unsigned long long keys[MAXC];
    __shared__ int sel[KPOOL];
    __shared__ float pl[KPOOL * HDIM];
    __shared__ double part[64];
    __shared__ double h1[HDIM];
    __shared__ double h2[HDIM / 2];

    bool inlds = (cnt <= MAXC);
    if (inlds) {
        for (int i = t; i < cnt; i += 64) {
            int n = s + i;
            keys[i] = ((unsigned long long)__float_as_uint(lastc[n]) << 32)
                    | (unsigned int)(~n);
        }
    }
    __syncthreads();

    // iterative top-K: key = (f32 bits << 32) | ~index (values >= 0 -> bits monotone)
    unsigned long long prev = ~0ull;
    for (int k = 0; k < KPOOL; ++k) {
        if (k < cnt) {
            unsigned long long best = 0ull;
            if (inlds) {
                for (int i = t; i < cnt; i += 64) {
                    unsigned long long key = keys[i];
                    if (key < prev && key > best) best = key;
                }
            } else {
                for (int n = s + t; n < e; n += 64) {
                    unsigned long long key =
                        ((unsigned long long)__float_as_uint(lastc[n]) << 32)
                        | (unsigned int)(~n);
                    if (key < prev && key > best) best = key;
                }
            }
            for (int off = 32; off; off >>= 1) {
                unsigned long long o = __shfl_down(best, off);
                if (o > best) best = o;
            }
            best = __shfl(best, 0);
            prev = best;
            if (t == 0) sel[k] = (int)(~((unsigned int)(best & 0xffffffffull)));
        } else {
            if (t == 0) sel[k] = -1;
        }
    }
    __syncthreads();

    for (int idx = t; idx < KPOOL * HDIM; idx += 64) {
        int k = idx >> 5, c = idx & 31;
        int n = sel[k];
        pl[idx] = (n >= 0) ? x[n * HDIM + c] : 0.0f;
    }
    __syncthreads();

    {
        int j = t & 31;
        int half = t >> 5;
        double acc = 0.0;
        int r0 = half * (KPOOL * HDIM / 2);
        for (int r = r0; r < r0 + KPOOL * HDIM / 2; ++r)
            acc += (double)pl[r] * (double)W1[r * HDIM + j];
        part[t] = acc;
    }
    __syncthreads();
    if (t < HDIM) {
        double v = part[t] + part[t + 32] + (double)b1[t];
        h1[t] = (v > 0.0) ? v : 0.0;
    }
    __syncthreads();

    if (t < HDIM / 2) {
        double a2 = (double)b2[t];
        for (int i = 0; i < HDIM; ++i) a2 += h1[i] * (double)W2[i * (HDIM / 2) + t];
        h2[t] = (a2 > 0.0) ? a2 : 0.0;
    }
    __syncthreads();

    if (t == 0) {
        double o = (double)b3[0];
        for (int i = 0; i < HDIM / 2; ++i) o += h2[i] * (double)W3[i];
        out[g] = (float)o;
    }
}

extern "C" void kernel_launch(void* const* d_in, const int* in_sizes, int n_in,
                              void* d_out, int out_size, void* d_ws, size_t ws_size,
                              hipStream_t stream) {
    const int*   xz    = (const int*)d_in[0];
    const int*   src   = (const int*)d_in[1];            // edge_index[0]
    const int*   dst   = (const int*)d_in[1] + N_EDGES;  // edge_index[1]
    const int*   batch = (const int*)d_in[2];
    const float* emb   = (const float*)d_in[3];
    const float* Wc    = (const float*)d_in[4];
    const float* bc    = (const float*)d_in[5];
    const float* gamma = (const float*)d_in[6];
    const float* beta  = (const float*)d_in[7];
    const float* rmean = (const float*)d_in[8];
    const float* rvar  = (const float*)d_in[9];
    const float* W1    = (const float*)d_in[10];
    const float* b1    = (const float*)d_in[11];
    const float* W2    = (const float*)d_in[12];
    const float* b2    = (const float*)d_in[13];
    const float* W3    = (const float*)d_in[14];
    const float* b3    = (const float*)d_in[15];
    float* out = (float*)d_out;

    // workspace carve-up (256B aligned). Total ~208 MB.
    char* p = (char*)d_ws;
    auto carve = [&](size_t bytes) {
        void* q = (void*)p;
        p += (bytes + 255) & ~size_t(255);
        return q;
    };
    int*   ghist = (int*)carve(HIST_SZ * 4);
    int*   gbase = (int*)carve(HIST_SZ * 4);
    int*   cur   = (int*)carve(HIST_SZ * 4);
    unsigned long long* stage = (unsigned long long*)carve((size_t)N_EDGES * 8);
    unsigned long long* csr2  = (unsigned long long*)carve((size_t)N_EDGES * 8);
    float* dinv  = (float*)carve(N_NODES * 4);
    int*   offs  = (int*)carve((N_NODES + 1) * 4);
    int*   start = (int*)carve((N_GRAPHS + 1) * 4);
    float* rs    = (float*)carve(NLAYERS * HDIM * 4);
    float* lastc = (float*)carve(N_NODES * 4);
    float* bufA  = (float*)carve((size_t)N_NODES * HDIM * 4);
    float* bufB  = (float*)carve((size_t)N_NODES * HDIM * 4);

    hipMemsetAsync(ghist, 0, HIST_SZ * 4, stream);

    k_hist<<<N_EDGES / 2048, 256, 0, stream>>>(dst, ghist);
    k_scan8k<<<1, 256, 0, stream>>>(ghist, gbase, cur);
    k_bin<<<N_EDGES / 2048, 256, 0, stream>>>(src, dst, cur, stage);
    k_build<<<NBUCKET, 256, 0, stream>>>(stage, gbase, dinv, offs, csr2);
    k_pack<<<N_EDGES / 256, 256, 0, stream>>>(dinv, csr2);
    k_bnprep<<<1, 128, 0, stream>>>(rvar, rs);
    k_starts<<<N_NODES / 256, 256, 0, stream>>>(batch, start);

    const int NG = (N_NODES * HDIM) / 256;
    k_embed_mm<<<NG, 256, 0, stream>>>(xz, emb, Wc + 0 * HDIM * HDIM, bufA);
    k_agg_mm<<<NG, 256, 0, stream>>>(bufA, dinv, offs, csr2,
        bc + 0 * HDIM, rmean + 0 * HDIM, rs + 0 * HDIM, gamma + 0 * HDIM, beta + 0 * HDIM,
        Wc + 1 * HDIM * HDIM, bufB);
    k_agg_mm<<<NG, 256, 0, stream>>>(bufB, dinv, offs, csr2,
        bc + 1 * HDIM, rmean + 1 * HDIM, rs + 1 * HDIM, gamma + 1 * HDIM, beta + 1 * HDIM,
        Wc + 2 * HDIM * HDIM, bufA);
    k_agg_last<<<NG, 256, 0, stream>>>(bufA, dinv, offs, csr2,
        bc + 2 * HDIM, rmean + 2 * HDIM, rs + 2 * HDIM, gamma + 2 * HDIM, beta + 2 * HDIM,
        bufB, lastc);

    k_pool_mlp<<<N_GRAPHS, 64, 0, stream>>>(bufB, lastc, start, W1, b1, W2, b2, W3, b3, out);
}

// Round 9
// 1211.972 us; speedup vs baseline: 1.9552x; 1.0135x over previous
//
#include <hip/hip_runtime.h>
#include <hip/hip_bf16.h>
#include <stdint.h>

#define N_NODES 524288
#define N_EDGES 4194304
#define N_GRAPHS 4096
#define HDIM 32
#define NLAYERS 3
#define KPOOL 30
#define MAXC 1024            // max nodes/graph handled in-LDS (avg 128; overflow -> fallback)

#define NBUCKET 1024
#define BSHIFT 9             // bucket = dst >> 9
#define NPB 512              // nodes per bucket
#define NCOPY 8              // per-XCD slice copies
#define HIST_SZ (NBUCKET * NCOPY)

// ---------- histogram of edges per (bucket, xcd-slice) ----------
__global__ void k_hist(const int* __restrict__ dst, int* __restrict__ ghist) {
    __shared__ int lh[NBUCKET];
    int t = threadIdx.x;
    for (int i = t; i < NBUCKET; i += 256) lh[i] = 0;
    __syncthreads();
    int base = blockIdx.x * 2048;
    for (int i = t; i < 2048; i += 256) {
        int d = dst[base + i];
        atomicAdd(&lh[d >> BSHIFT], 1);
    }
    __syncthreads();
    int c = blockIdx.x & 7;
    for (int i = t; i < NBUCKET; i += 256) {
        int v = lh[i];
        if (v) atomicAdd(&ghist[i * NCOPY + c], v);
    }
}

// ---------- exclusive scan of 8192 counts -> gbase, cur ----------
__global__ void k_scan8k(const int* __restrict__ ghist, int* __restrict__ gbase,
                         int* __restrict__ cur) {
    __shared__ int tmp[256];
    int t = threadIdx.x;
    int loc[32];
    int s = 0;
    for (int k = 0; k < 32; ++k) { loc[k] = ghist[t * 32 + k]; s += loc[k]; }
    tmp[t] = s;
    __syncthreads();
    for (int d = 1; d < 256; d <<= 1) {
        int a = (t >= d) ? tmp[t - d] : 0;
        __syncthreads();
        tmp[t] += a;
        __syncthreads();
    }
    int run = tmp[t] - s;
    for (int k = 0; k < 32; ++k) {
        gbase[t * 32 + k] = run;
        cur[t * 32 + k] = run;
        run += loc[k];
    }
}

// ---------- bin edges into bucket/slice staging: (src<<32)|(eid<<9)|dstLocal ----------
__global__ void k_bin(const int* __restrict__ src, const int* __restrict__ dst,
                      int* __restrict__ cur, unsigned long long* __restrict__ stage) {
    int base = blockIdx.x * 2048;
    int c = blockIdx.x & 7;
    int t = threadIdx.x;
    for (int i = t; i < 2048; i += 256) {
        int e = base + i;
        int d = dst[e];
        int b = d >> BSHIFT;
        int pos = atomicAdd(&cur[b * NCOPY + c], 1);
        unsigned long long rec = ((unsigned long long)(unsigned)src[e] << 32)
                               | (unsigned)((e << BSHIFT) | (d & (NPB - 1)));
        stage[pos] = rec;
    }
}

// ---------- per-bucket: deg/dinv + offs + stable csr build (sorted by eid) ----------
__global__ void k_build(const unsigned long long* __restrict__ stage,
                        const int* __restrict__ gbase,
                        float* __restrict__ dinv, int* __restrict__ offs,
                        unsigned long long* __restrict__ csr2) {
    __shared__ int cnt[NPB];
    __shared__ int sstart[NPB];
    __shared__ int tmp[256];
    int b = blockIdx.x, t = threadIdx.x;
    int s0 = gbase[b * NCOPY];
    int s1 = (b == NBUCKET - 1) ? N_EDGES : gbase[(b + 1) * NCOPY];
    for (int j = t; j < NPB; j += 256) cnt[j] = 0;
    __syncthreads();
    for (int i = s0 + t; i < s1; i += 256) {
        unsigned key = (unsigned)stage[i];
        atomicAdd(&cnt[key & (NPB - 1)], 1);
    }
    __syncthreads();
    int j0 = 2 * t, j1 = 2 * t + 1;
    int a0 = cnt[j0], a1 = cnt[j1];
    // dinv = f32(1 / f32(sqrt(deg+1)))  (identical op sequence to reference)
    {
        float d0 = (float)(a0 + 1);
        float q0 = (float)sqrt((double)d0);
        dinv[b * NPB + j0] = (float)(1.0 / (double)q0);
        float d1 = (float)(a1 + 1);
        float q1 = (float)sqrt((double)d1);
        dinv[b * NPB + j1] = (float)(1.0 / (double)q1);
    }
    int s = a0 + a1;
    tmp[t] = s;
    __syncthreads();
    for (int d = 1; d < 256; d <<= 1) {
        int a = (t >= d) ? tmp[t - d] : 0;
        __syncthreads();
        tmp[t] += a;
        __syncthreads();
    }
    int run = tmp[t] - s;
    sstart[j0] = run;
    sstart[j1] = run + a0;
    offs[b * NPB + j0] = s0 + run;
    offs[b * NPB + j1] = s0 + run + a0;
    if (b == NBUCKET - 1 && t == 255) offs[N_NODES] = N_EDGES;
    cnt[j0] = run;          // reuse as scatter cursors
    cnt[j1] = run + a0;
    __syncthreads();
    // scatter into this bucket's csr window (L2-resident)
    for (int i = s0 + t; i < s1; i += 256) {
        unsigned long long v = stage[i];
        int pos = s0 + atomicAdd(&cnt[(unsigned)v & (NPB - 1)], 1);
        csr2[pos] = v;
    }
    __syncthreads();
    // per-node insertion sort by packed key (== eid order within a node)
    for (int jj = 0; jj < 2; ++jj) {
        int j = 2 * t + jj;
        int beg = s0 + sstart[j];
        int end = s0 + cnt[j];
        for (int i = beg + 1; i < end; ++i) {
            unsigned long long v = csr2[i];
            unsigned kv = (unsigned)v;
            int q = i - 1;
            while (q >= beg && (unsigned)csr2[q] > kv) { csr2[q + 1] = csr2[q]; --q; }
            csr2[q + 1] = v;
        }
    }
}

// ---------- pack dinv[src] into the (now dead) low word of each record ----------
__global__ void k_pack(const float* __restrict__ dinv, unsigned long long* __restrict__ csr2) {
    int i = blockIdx.x * 256 + threadIdx.x;
    if (i < N_EDGES) {
        unsigned long long r = csr2[i];
        int s = (int)(r >> 32);
        csr2[i] = (r & 0xffffffff00000000ull) | (unsigned)__float_as_uint(dinv[s]);
    }
}

// ---------- rs = f32(1 / f32(sqrt(f32(rvar + 1e-5)))) ----------
__global__ void k_bnprep(const float* __restrict__ rvar, float* __restrict__ rs) {
    int i = threadIdx.x;
    if (i < NLAYERS * HDIM) {
        float rv = __fadd_rn(rvar[i], 1e-5f);
        float sq = (float)sqrt((double)rv);
        rs[i] = (float)(1.0 / (double)sq);
    }
}

// ---------- fused embed + matmul layer0 ----------
__global__ void k_embed_mm(const int* __restrict__ xz, const float* __restrict__ emb,
                           const float* __restrict__ Wc, float* __restrict__ h) {
    __shared__ float Wl[HDIM * HDIM];
    __shared__ float xt[256];
    int t = threadIdx.x;
    int base = blockIdx.x * 256;
    for (int i = t; i < HDIM * HDIM; i += 256) Wl[i] = Wc[i];
    {
        int gid = base + t;
        int n = gid >> 5, c = gid & 31;
        xt[t] = emb[xz[n] * HDIM + c];
    }
    __syncthreads();
    int nl = t >> 5, c = t & 31;
    float acc = 0.0f;
#pragma unroll
    for (int k = 0; k < HDIM; ++k) acc = __fmaf_rn(xt[nl * HDIM + k], Wl[k * HDIM + c], acc);
    h[base + t] = acc;
}

// ---------- agg phase: strict f32 op order, 8-deep software pipeline ----------
__device__ __forceinline__ float agg_phase(const float* __restrict__ h,
                                           const float* __restrict__ dinv,
                                           const int* __restrict__ offs,
                                           const unsigned long long* __restrict__ csr2,
                                           const float* __restrict__ bc,
                                           const float* __restrict__ rmean,
                                           const float* __restrict__ rs,
                                           const float* __restrict__ gamma,
                                           const float* __restrict__ beta,
                                           int gid) {
    int n = gid >> 5, c = gid & 31;
    float di = dinv[n];
    float hself = h[gid];                 // hoisted: overlaps with edge loop
    float accE = 0.0f;  // np.add.at: sequential in edge-id order
    int beg = offs[n], end = offs[n + 1];
    int i = beg;
    // 8-wide batches (avg degree is 8): 8 independent record loads ->
    // 8 independent h-row gathers in flight, then the 8 ordered adds.
    for (; i + 8 <= end; i += 8) {
        unsigned long long r0 = csr2[i];
        unsigned long long r1 = csr2[i + 1];
        unsigned long long r2 = csr2[i + 2];
        unsigned long long r3 = csr2[i + 3];
        unsigned long long r4 = csr2[i + 4];
        unsigned long long r5 = csr2[i + 5];
        unsigned long long r6 = csr2[i + 6];
        unsigned long long r7 = csr2[i + 7];
        float h0 = h[(int)(r0 >> 32) * HDIM + c];
        float h1 = h[(int)(r1 >> 32) * HDIM + c];
        float h2 = h[(int)(r2 >> 32) * HDIM + c];
        float h3 = h[(int)(r3 >> 32) * HDIM + c];
        float h4 = h[(int)(r4 >> 32) * HDIM + c];
        float h5 = h[(int)(r5 >> 32) * HDIM + c];
        float h6 = h[(int)(r6 >> 32) * HDIM + c];
        float h7 = h[(int)(r7 >> 32) * HDIM + c];
        accE = __fadd_rn(accE, __fmul_rn(h0, __fmul_rn(__uint_as_float((unsigned)r0), di)));
        accE = __fadd_rn(accE, __fmul_rn(h1, __fmul_rn(__uint_as_float((unsigned)r1), di)));
        accE = __fadd_rn(accE, __fmul_rn(h2, __fmul_rn(__uint_as_float((unsigned)r2), di)));
        accE = __fadd_rn(accE, __fmul_rn(h3, __fmul_rn(__uint_as_float((unsigned)r3), di)));
        accE = __fadd_rn(accE, __fmul_rn(h4, __fmul_rn(__uint_as_float((unsigned)r4), di)));
        accE = __fadd_rn(accE, __fmul_rn(h5, __fmul_rn(__uint_as_float((unsigned)r5), di)));
        accE = __fadd_rn(accE, __fmul_rn(h6, __fmul_rn(__uint_as_float((unsigned)r6), di)));
        accE = __fadd_rn(accE, __fmul_rn(h7, __fmul_rn(__uint_as_float((unsigned)r7), di)));
    }
    for (; i + 4 <= end; i += 4) {
        unsigned long long r0 = csr2[i];
        unsigned long long r1 = csr2[i + 1];
        unsigned long long r2 = csr2[i + 2];
        unsigned long long r3 = csr2[i + 3];
        float h0 = h[(int)(r0 >> 32) * HDIM + c];
        float h1 = h[(int)(r1 >> 32) * HDIM + c];
        float h2 = h[(int)(r2 >> 32) * HDIM + c];
        float h3 = h[(int)(r3 >> 32) * HDIM + c];
        accE = __fadd_rn(accE, __fmul_rn(h0, __fmul_rn(__uint_as_float((unsigned)r0), di)));
        accE = __fadd_rn(accE, __fmul_rn(h1, __fmul_rn(__uint_as_float((unsigned)r1), di)));
        accE = __fadd_rn(accE, __fmul_rn(h2, __fmul_rn(__uint_as_float((unsigned)r2), di)));
        accE = __fadd_rn(accE, __fmul_rn(h3, __fmul_rn(__uint_as_float((unsigned)r3), di)));
    }
    for (; i < end; ++i) {
        unsigned long long r = csr2[i];
        float hv = h[(int)(r >> 32) * HDIM + c];
        float dv = __uint_as_float((unsigned)r);
        accE = __fadd_rn(accE, __fmul_rn(hv, __fmul_rn(dv, di)));
    }
    float sn = __fmul_rn(di, di);
    float t1 = __fmul_rn(hself, sn);
    float a2 = __fadd_rn(accE, t1);
    float a3 = __fadd_rn(a2, bc[c]);
    float tt = __fsub_rn(a3, rmean[c]);
    float u  = __fmul_rn(tt, rs[c]);
    float v  = __fmul_rn(u, gamma[c]);
    float xn = __fadd_rn(v, beta[c]);
    return (xn > 0.0f) ? xn : 0.0f;
}

// ---------- fused agg(BN,ReLU) + next-layer matmul ----------
__global__ void k_agg_mm(const float* __restrict__ h, const float* __restrict__ dinv,
                         const int* __restrict__ offs,
                         const unsigned long long* __restrict__ csr2,
                         const float* __restrict__ bc, const float* __restrict__ rmean,
                         const float* __restrict__ rs, const float* __restrict__ gamma,
                         const float* __restrict__ beta,
                         const float* __restrict__ Wnext, float* __restrict__ hout) {
    __shared__ float Wl[HDIM * HDIM];
    __shared__ float xt[256];
    int t = threadIdx.x;
    int base = blockIdx.x * 256;
    for (int i = t; i < HDIM * HDIM; i += 256) Wl[i] = Wnext[i];
    xt[t] = agg_phase(h, dinv, offs, csr2, bc, rmean, rs, gamma, beta, base + t);
    __syncthreads();
    int nl = t >> 5, c = t & 31;
    float acc = 0.0f;
#pragma unroll
    for (int k = 0; k < HDIM; ++k) acc = __fmaf_rn(xt[nl * HDIM + k], Wl[k * HDIM + c], acc);
    hout[base + t] = acc;
}

// ---------- last agg: also emit dense channel-31 array for the sort-pool ----------
__global__ void k_agg_last(const float* __restrict__ h, const float* __restrict__ dinv,
                           const int* __restrict__ offs,
                           const unsigned long long* __restrict__ csr2,
                           const float* __restrict__ bc, const float* __restrict__ rmean,
                           const float* __restrict__ rs, const float* __restrict__ gamma,
                           const float* __restrict__ beta, float* __restrict__ xout,
                           float* __restrict__ lastc) {
    int gid = blockIdx.x * 256 + threadIdx.x;
    float v = agg_phase(h, dinv, offs, csr2, bc, rmean, rs, gamma, beta, gid);
    xout[gid] = v;
    if ((gid & 31) == 31) lastc[gid >> 5] = v;
}

// ---------- per-graph starts ----------
__global__ void k_starts(const int* __restrict__ batch, int* __restrict__ start) {
    int n = blockIdx.x * 256 + threadIdx.x;
    if (n >= N_NODES) return;
    int bn = batch[n];
    int bp = (n == 0) ? -1 : batch[n - 1];
    for (int g = bp + 1; g <= bn; ++g) start[g] = n;
    if (n == N_NODES - 1) {
        for (int g = bn + 1; g <= N_GRAPHS; ++g) start[g] = N_NODES;
    }
}

// ---------- sort-pool (keys cached in LDS) + MLP (f64 accumulate) ----------
__global__ void k_pool_mlp(const float* __restrict__ x, const float* __restrict__ lastc,
                           const int* __restrict__ start,
                           const float* __restrict__ W1, const float* __restrict__ b1,
                           const float* __restrict__ W2, const float* __restrict__ b2,
                           const float* __restrict__ W3, const float* __restrict__ b3,
                           float* __restrict__ out) {
    int g = blockIdx.x;
    int t = threadIdx.x;  // 64 threads = 1 wave
    int s = start[g], e = start[g + 1];
    int cnt = e - s;

    __shared__ unsigned long long keys[MAXC];
    __shared__ int sel[KPOOL];
    __shared__ float pl[KPOOL * HDIM];
    __shared__ double part[64];
    __shared__ double h1[HDIM];
    __shared__ double h2[HDIM / 2];

    bool inlds = (cnt <= MAXC);
    if (inlds) {
        for (int i = t; i < cnt; i += 64) {
            int n = s + i;
            keys[i] = ((unsigned long long)__float_as_uint(lastc[n]) << 32)
                    | (unsigned int)(~n);
        }
    }
    __syncthreads();

    unsigned long long prev = ~0ull;
    for (int k = 0; k < KPOOL; ++k) {
        if (k < cnt) {
            unsigned long long best = 0ull;
            if (inlds) {
                for (int i = t; i < cnt; i += 64) {
                    unsigned long long key = keys[i];
                    if (key < prev && key > best) best = key;
                }
            } else {
                for (int n = s + t; n < e; n += 64) {
                    unsigned long long key =
                        ((unsigned long long)__float_as_uint(lastc[n]) << 32)
                        | (unsigned int)(~n);
                    if (key < prev && key > best) best = key;
                }
            }
            for (int off = 32; off; off >>= 1) {
                unsigned long long o = __shfl_down(best, off);
                if (o > best) best = o;
            }
            best = __shfl(best, 0);
            prev = best;
            if (t == 0) sel[k] = (int)(~((unsigned int)(best & 0xffffffffull)));
        } else {
            if (t == 0) sel[k] = -1;
        }
    }
    __syncthreads();

    for (int idx = t; idx < KPOOL * HDIM; idx += 64) {
        int k = idx >> 5, c = idx & 31;
        int n = sel[k];
        pl[idx] = (n >= 0) ? x[n * HDIM + c] : 0.0f;
    }
    __syncthreads();

    {
        int j = t & 31;
        int half = t >> 5;
        double acc = 0.0;
        int r0 = half * (KPOOL * HDIM / 2);
        for (int r = r0; r < r0 + KPOOL * HDIM / 2; ++r)
            acc += (double)pl[r] * (double)W1[r * HDIM + j];
        part[t] = acc;
    }
    __syncthreads();
    if (t < HDIM) {
        double v = part[t] + part[t + 32] + (double)b1[t];
        h1[t] = (v > 0.0) ? v : 0.0;
    }
    __syncthreads();

    if (t < HDIM / 2) {
        double a2 = (double)b2[t];
        for (int i = 0; i < HDIM; ++i) a2 += h1[i] * (double)W2[i * (HDIM / 2) + t];
        h2[t] = (a2 > 0.0) ? a2 : 0.0;
    }
    __syncthreads();

    if (t == 0) {
        double o = (double)b3[0];
        for (int i = 0; i < HDIM / 2; ++i) o += h2[i] * (double)W3[i];
        out[g] = (float)o;
    }
}

extern "C" void kernel_launch(void* const* d_in, const int* in_sizes, int n_in,
                              void* d_out, int out_size, void* d_ws, size_t ws_size,
                              hipStream_t stream) {
    const int*   xz    = (const int*)d_in[0];
    const int*   src   = (const int*)d_in[1];            // edge_index[0]
    const int*   dst   = (const int*)d_in[1] + N_EDGES;  // edge_index[1]
    const int*   batch = (const int*)d_in[2];
    const float* emb   = (const float*)d_in[3];
    const float* Wc    = (const float*)d_in[4];
    const float* bc    = (const float*)d_in[5];
    const float* gamma = (const float*)d_in[6];
    const float* beta  = (const float*)d_in[7];
    const float* rmean = (const float*)d_in[8];
    const float* rvar  = (const float*)d_in[9];
    const float* W1    = (const float*)d_in[10];
    const float* b1    = (const float*)d_in[11];
    const float* W2    = (const float*)d_in[12];
    const float* b2    = (const float*)d_in[13];
    const float* W3    = (const float*)d_in[14];
    const float* b3    = (const float*)d_in[15];
    float* out = (float*)d_out;

    // workspace carve-up (256B aligned). Total ~208 MB.
    char* p = (char*)d_ws;
    auto carve = [&](size_t bytes) {
        void* q = (void*)p;
        p += (bytes + 255) & ~size_t(255);
        return q;
    };
    int*   ghist = (int*)carve(HIST_SZ * 4);
    int*   gbase = (int*)carve(HIST_SZ * 4);
    int*   cur   = (int*)carve(HIST_SZ * 4);
    unsigned long long* stage = (unsigned long long*)carve((size_t)N_EDGES * 8);
    unsigned long long* csr2  = (unsigned long long*)carve((size_t)N_EDGES * 8);
    float* dinv  = (float*)carve(N_NODES * 4);
    int*   offs  = (int*)carve((N_NODES + 1) * 4);
    int*   start = (int*)carve((N_GRAPHS + 1) * 4);
    float* rs    = (float*)carve(NLAYERS * HDIM * 4);
    float* lastc = (float*)carve(N_NODES * 4);
    float* bufA  = (float*)carve((size_t)N_NODES * HDIM * 4);
    float* bufB  = (float*)carve((size_t)N_NODES * HDIM * 4);

    hipMemsetAsync(ghist, 0, HIST_SZ * 4, stream);

    k_hist<<<N_EDGES / 2048, 256, 0, stream>>>(dst, ghist);
    k_scan8k<<<1, 256, 0, stream>>>(ghist, gbase, cur);
    k_bin<<<N_EDGES / 2048, 256, 0, stream>>>(src, dst, cur, stage);
    k_build<<<NBUCKET, 256, 0, stream>>>(stage, gbase, dinv, offs, csr2);
    k_pack<<<N_EDGES / 256, 256, 0, stream>>>(dinv, csr2);
    k_bnprep<<<1, 128, 0, stream>>>(rvar, rs);
    k_starts<<<N_NODES / 256, 256, 0, stream>>>(batch, start);

    const int NG = (N_NODES * HDIM) / 256;
    k_embed_mm<<<NG, 256, 0, stream>>>(xz, emb, Wc + 0 * HDIM * HDIM, bufA);
    k_agg_mm<<<NG, 256, 0, stream>>>(bufA, dinv, offs, csr2,
        bc + 0 * HDIM, rmean + 0 * HDIM, rs + 0 * HDIM, gamma + 0 * HDIM, beta + 0 * HDIM,
        Wc + 1 * HDIM * HDIM, bufB);
    k_agg_mm<<<NG, 256, 0, stream>>>(bufB, dinv, offs, csr2,
        bc + 1 * HDIM, rmean + 1 * HDIM, rs + 1 * HDIM, gamma + 1 * HDIM, beta + 1 * HDIM,
        Wc + 2 * HDIM * HDIM, bufA);
    k_agg_last<<<NG, 256, 0, stream>>>(bufA, dinv, offs, csr2,
        bc + 2 * HDIM, rmean + 2 * HDIM, rs + 2 * HDIM, gamma + 2 * HDIM, beta + 2 * HDIM,
        bufB, lastc);

    k_pool_mlp<<<N_GRAPHS, 64, 0, stream>>>(bufB, lastc, start, W1, b1, W2, b2, W3, b3, out);
}